// Round 2
// baseline (1840.178 us; speedup 1.0000x reference)
//
#include <hip/hip_runtime.h>
#include <hip/hip_bf16.h>

#define D_MODEL 1024
#define D_INNER 2048
#define D_CONV  4
#define DT_RANK 64
#define D_STATE 16
#define LSEQ    2048

typedef __attribute__((ext_vector_type(8))) short  short8;
typedef __attribute__((ext_vector_type(4))) float  float4v;
typedef __hip_bfloat16 bf16;

static __device__ __forceinline__ float b2f(bf16 v) { return __bfloat162float(v); }
static __device__ __forceinline__ bf16  f2b(float v) { return __float2bfloat16(v); }

// ----------------------------------------------------------- fp32 -> bf16 ----
__global__ void cast4_kernel(const float* __restrict__ in, bf16* __restrict__ out, int n4) {
    int i = blockIdx.x * 256 + threadIdx.x;
    if (i < n4) {
        float4v v = ((const float4v*)in)[i];
        bf16* o = out + i * 4;
        o[0] = f2b(v[0]); o[1] = f2b(v[1]); o[2] = f2b(v[2]); o[3] = f2b(v[3]);
    }
}

// ---------------------------------------------------------------- RMSNorm ----
__global__ void rms_kernel(const float* __restrict__ x, const float* __restrict__ nw,
                           bf16* __restrict__ xn) {
    int l = blockIdx.x, t = threadIdx.x;           // 256 threads, 4 elems each
    float4v v = ((const float4v*)(x + (size_t)l * D_MODEL))[t];
    float ssq = v[0]*v[0] + v[1]*v[1] + v[2]*v[2] + v[3]*v[3];
    for (int o = 32; o > 0; o >>= 1) ssq += __shfl_down(ssq, o);
    __shared__ float part[4];
    int lane = t & 63, wid = t >> 6;
    if (lane == 0) part[wid] = ssq;
    __syncthreads();
    float tot = part[0] + part[1] + part[2] + part[3];
    float sc = rsqrtf(tot * (1.0f / D_MODEL) + 1e-5f);
    float4v nv = ((const float4v*)nw)[t];
    bf16* op = xn + (size_t)l * D_MODEL + t * 4;
    op[0] = f2b(v[0] * sc * nv[0]);
    op[1] = f2b(v[1] * sc * nv[1]);
    op[2] = f2b(v[2] * sc * nv[2]);
    op[3] = f2b(v[3] * sc * nv[3]);
}

// ------------------------------------------------------- generic NT GEMM ----
// C[M,N] = A[M,K] * B[N,K]^T, bf16 in, fp32 acc. lda = ldb = K.
// MODE 0: outB = bf16(acc)                        (xz)
// MODE 1: outF = acc (ld 96); n<64 -> outB bf16   (dbc + dt cast)
// MODE 2: outB = bf16(softplus(acc + bias[n]))    (delta)
// MODE 3: outF = acc + resid[m*N+n]  (fp32 out)   (final out + residual)
#define LDK 56  // padded LDS row stride (bf16 elems): 112 B, 16B-aligned, 2-way banks

template <int MODE>
__global__ __launch_bounds__(256)
void gemm_nt(const bf16* __restrict__ Ab, const bf16* __restrict__ Bb,
             int M, int N, int K,
             float* __restrict__ outF, bf16* __restrict__ outB,
             const float* __restrict__ bias, const float* __restrict__ resid) {
    __shared__ short As[128 * LDK];
    __shared__ short Bs[128 * LDK];
    const short* Ap = (const short*)Ab;
    const short* Bp = (const short*)Bb;

    int t = threadIdx.x;
    int mBase = blockIdx.y * 128;
    int nBase = blockIdx.x * 128;
    int lane = t & 63, wid = t >> 6;
    int wm = (wid >> 1) * 64, wn = (wid & 1) * 64;
    int lr = lane & 15, quad = lane >> 4;

    float4v acc[4][4] = {};

    for (int kt = 0; kt < K; kt += 32) {
        #pragma unroll
        for (int it = 0; it < 2; ++it) {
            int cidx = t + it * 256;        // 0..511
            int row  = cidx >> 2;           // 0..127
            int k8   = (cidx & 3) * 8;      // 0,8,16,24
            short8 av = {0,0,0,0,0,0,0,0};
            short8 bv = {0,0,0,0,0,0,0,0};
            int gm = mBase + row;
            int gn = nBase + row;
            if (gm < M) av = *(const short8*)(Ap + (size_t)gm * K + kt + k8);
            if (gn < N) bv = *(const short8*)(Bp + (size_t)gn * K + kt + k8);
            *(short8*)&As[row * LDK + k8] = av;
            *(short8*)&Bs[row * LDK + k8] = bv;
        }
        __syncthreads();
        short8 af[4], bfr[4];
        #pragma unroll
        for (int i = 0; i < 4; ++i)
            af[i] = *(const short8*)&As[(wm + i * 16 + lr) * LDK + quad * 8];
        #pragma unroll
        for (int j = 0; j < 4; ++j)
            bfr[j] = *(const short8*)&Bs[(wn + j * 16 + lr) * LDK + quad * 8];
        #pragma unroll
        for (int i = 0; i < 4; ++i)
            #pragma unroll
            for (int j = 0; j < 4; ++j)
                acc[i][j] = __builtin_amdgcn_mfma_f32_16x16x32_bf16(af[i], bfr[j], acc[i][j], 0, 0, 0);
        __syncthreads();
    }

    // epilogue: D[row = quad*4+reg][col = lane&15] within each 16x16 tile
    #pragma unroll
    for (int i = 0; i < 4; ++i) {
        #pragma unroll
        for (int j = 0; j < 4; ++j) {
            #pragma unroll
            for (int r = 0; r < 4; ++r) {
                int gm = mBase + wm + i * 16 + quad * 4 + r;
                int gn = nBase + wn + j * 16 + lr;
                if (gm < M && gn < N) {
                    float v = acc[i][j][r];
                    if (MODE == 0) {
                        outB[(size_t)gm * N + gn] = f2b(v);
                    } else if (MODE == 1) {
                        outF[(size_t)gm * N + gn] = v;
                        if (gn < DT_RANK) outB[(size_t)gm * DT_RANK + gn] = f2b(v);
                    } else if (MODE == 2) {
                        v += bias[gn];
                        v = (v > 20.0f) ? v : log1pf(__expf(v));
                        outB[(size_t)gm * N + gn] = f2b(v);
                    } else { // MODE 3
                        outF[(size_t)gm * N + gn] = v + resid[(size_t)gm * N + gn];
                    }
                }
            }
        }
    }
}

// ---------------------------------------------- depthwise causal conv+SiLU ----
__global__ void conv_kernel(const bf16* __restrict__ xz, const float* __restrict__ cw,
                            const float* __restrict__ cb, bf16* __restrict__ xsb) {
    int idx = blockIdx.x * 256 + threadIdx.x;   // over LSEQ*D_INNER
    int c = idx & (D_INNER - 1);
    int l = idx >> 11;
    float w0 = cw[c * 4 + 0];
    float w1 = cw[c * 4 + 1];
    float w2 = cw[c * 4 + 2];
    float w3 = cw[c * 4 + 3];
    float acc = cb[c];
    const bf16* col = xz + c;                   // xc = xz[:, :2048], row stride 4096
    if (l >= 3) acc += b2f(col[(size_t)(l - 3) * (2 * D_INNER)]) * w0;
    if (l >= 2) acc += b2f(col[(size_t)(l - 2) * (2 * D_INNER)]) * w1;
    if (l >= 1) acc += b2f(col[(size_t)(l - 1) * (2 * D_INNER)]) * w2;
    acc += b2f(col[(size_t)l * (2 * D_INNER)]) * w3;
    float s = acc * (1.0f / (1.0f + __expf(-acc)));   // SiLU
    xsb[idx] = f2b(s);
}

// ------------------------------------------------------- selective scan ----
// thread = (d, n): d = blk*16 + (tid>>4), n = tid&15. 128 blocks x 256 thr.
__global__ void scan_kernel(const bf16* __restrict__ delta, const bf16* __restrict__ xsb,
                            const float* __restrict__ dbc, const bf16* __restrict__ xz,
                            const float* __restrict__ A_log, const float* __restrict__ Dw,
                            bf16* __restrict__ yg) {
    int t = threadIdx.x;
    int n = t & 15, dl = t >> 4;
    int d = blockIdx.x * 16 + dl;
    float A  = -__expf(A_log[(size_t)d * D_STATE + n]);
    float Dd = Dw[d];
    float h = 0.0f;
    for (int l = 0; l < LSEQ; ++l) {
        float dv = b2f(delta[(size_t)l * D_INNER + d]);
        float xv = b2f(xsb[(size_t)l * D_INNER + d]);
        float Bv = dbc[(size_t)l * 96 + DT_RANK + n];
        float Cv = dbc[(size_t)l * 96 + DT_RANK + D_STATE + n];
        h = __expf(dv * A) * h + dv * Bv * xv;
        float p = h * Cv;
        p += __shfl_xor(p, 1);
        p += __shfl_xor(p, 2);
        p += __shfl_xor(p, 4);
        p += __shfl_xor(p, 8);
        if (n == 0) {
            float r = b2f(xz[(size_t)l * (2 * D_INNER) + D_INNER + d]);  // res branch
            float y = p + xv * Dd;
            float g = r * (1.0f / (1.0f + __expf(-r)));                  // silu(res)
            yg[(size_t)l * D_INNER + d] = f2b(y * g);
        }
    }
}

// -------------------------------------------------------------- launcher ----
extern "C" void kernel_launch(void* const* d_in, const int* in_sizes, int n_in,
                              void* d_out, int out_size, void* d_ws, size_t ws_size,
                              hipStream_t stream) {
    const float* x       = (const float*)d_in[0];
    const float* W_in    = (const float*)d_in[1];
    const float* conv_w  = (const float*)d_in[2];
    const float* conv_b  = (const float*)d_in[3];
    const float* W_xproj = (const float*)d_in[4];
    const float* W_dt    = (const float*)d_in[5];
    const float* b_dt    = (const float*)d_in[6];
    const float* A_log   = (const float*)d_in[7];
    const float* Dw      = (const float*)d_in[8];
    const float* W_out   = (const float*)d_in[9];
    const float* norm_w  = (const float*)d_in[10];

    char* w = (char*)d_ws;
    bf16* W_in_b    = (bf16*)w; w += (size_t)2 * D_INNER * D_MODEL * 2;     // 8 MB
    bf16* W_out_b   = (bf16*)w; w += (size_t)D_MODEL * D_INNER * 2;         // 4 MB
    bf16* W_xproj_b = (bf16*)w; w += (size_t)96 * D_INNER * 2;              // 384 KB
    bf16* W_dt_b    = (bf16*)w; w += (size_t)D_INNER * DT_RANK * 2;         // 256 KB
    bf16* xn        = (bf16*)w; w += (size_t)LSEQ * D_MODEL * 2;            // 4 MB
    bf16* xz        = (bf16*)w; w += (size_t)LSEQ * 2 * D_INNER * 2;        // 16 MB
    bf16* xsb       = (bf16*)w; w += (size_t)LSEQ * D_INNER * 2;            // 8 MB
    float* dbc      = (float*)w; w += (size_t)LSEQ * 96 * 4;                // 768 KB
    bf16* dtb       = (bf16*)w; w += (size_t)LSEQ * DT_RANK * 2;            // 256 KB
    bf16* delta     = (bf16*)w; w += (size_t)LSEQ * D_INNER * 2;            // 8 MB
    bf16* yg        = (bf16*)w; w += (size_t)LSEQ * D_INNER * 2;            // 8 MB

    cast4_kernel<<<(2 * D_INNER * D_MODEL / 4 + 255) / 256, 256, 0, stream>>>(W_in, W_in_b, 2 * D_INNER * D_MODEL / 4);
    cast4_kernel<<<(D_MODEL * D_INNER / 4 + 255) / 256, 256, 0, stream>>>(W_out, W_out_b, D_MODEL * D_INNER / 4);
    cast4_kernel<<<(96 * D_INNER / 4 + 255) / 256, 256, 0, stream>>>(W_xproj, W_xproj_b, 96 * D_INNER / 4);
    cast4_kernel<<<(D_INNER * DT_RANK / 4 + 255) / 256, 256, 0, stream>>>(W_dt, W_dt_b, D_INNER * DT_RANK / 4);

    rms_kernel<<<LSEQ, 256, 0, stream>>>(x, norm_w, xn);

    gemm_nt<0><<<dim3(4096 / 128, 2048 / 128), 256, 0, stream>>>(
        xn, W_in_b, 2048, 4096, 1024, nullptr, xz, nullptr, nullptr);

    conv_kernel<<<(LSEQ * D_INNER) / 256, 256, 0, stream>>>(xz, conv_w, conv_b, xsb);

    gemm_nt<1><<<dim3(1, 2048 / 128), 256, 0, stream>>>(
        xsb, W_xproj_b, 2048, 96, 2048, dbc, dtb, nullptr, nullptr);

    gemm_nt<2><<<dim3(2048 / 128, 2048 / 128), 256, 0, stream>>>(
        dtb, W_dt_b, 2048, 2048, 64, nullptr, delta, b_dt, nullptr);

    scan_kernel<<<D_INNER / 16, 256, 0, stream>>>(delta, xsb, dbc, xz, A_log, Dw, yg);

    gemm_nt<3><<<dim3(1024 / 128, 2048 / 128), 256, 0, stream>>>(
        yg, W_out_b, 2048, 1024, 2048, (float*)d_out, nullptr, nullptr, x);
}

// Round 3
// 450.098 us; speedup vs baseline: 4.0884x; 4.0884x over previous
//
#include <hip/hip_runtime.h>
#include <hip/hip_bf16.h>

#define D_MODEL 1024
#define D_INNER 2048
#define D_CONV  4
#define DT_RANK 64
#define D_STATE 16
#define LSEQ    2048
#define CHUNK   64
#define NCHUNK  (LSEQ / CHUNK)   // 32
#define DN      (D_INNER * D_STATE)  // 32768

typedef __attribute__((ext_vector_type(8))) short  short8;
typedef __attribute__((ext_vector_type(4))) float  float4v;
typedef __hip_bfloat16 bf16;

static __device__ __forceinline__ float b2f(bf16 v) { return __bfloat162float(v); }
static __device__ __forceinline__ bf16  f2b(float v) { return __float2bfloat16(v); }

// ----------------------------------------------------------- fp32 -> bf16 ----
__global__ void cast4_kernel(const float* __restrict__ in, bf16* __restrict__ out, int n4) {
    int i = blockIdx.x * 256 + threadIdx.x;
    if (i < n4) {
        float4v v = ((const float4v*)in)[i];
        bf16* o = out + i * 4;
        o[0] = f2b(v[0]); o[1] = f2b(v[1]); o[2] = f2b(v[2]); o[3] = f2b(v[3]);
    }
}

// ---------------------------------------------------------------- RMSNorm ----
__global__ void rms_kernel(const float* __restrict__ x, const float* __restrict__ nw,
                           bf16* __restrict__ xn) {
    int l = blockIdx.x, t = threadIdx.x;           // 256 threads, 4 elems each
    float4v v = ((const float4v*)(x + (size_t)l * D_MODEL))[t];
    float ssq = v[0]*v[0] + v[1]*v[1] + v[2]*v[2] + v[3]*v[3];
    for (int o = 32; o > 0; o >>= 1) ssq += __shfl_down(ssq, o);
    __shared__ float part[4];
    int lane = t & 63, wid = t >> 6;
    if (lane == 0) part[wid] = ssq;
    __syncthreads();
    float tot = part[0] + part[1] + part[2] + part[3];
    float sc = rsqrtf(tot * (1.0f / D_MODEL) + 1e-5f);
    float4v nv = ((const float4v*)nw)[t];
    bf16* op = xn + (size_t)l * D_MODEL + t * 4;
    op[0] = f2b(v[0] * sc * nv[0]);
    op[1] = f2b(v[1] * sc * nv[1]);
    op[2] = f2b(v[2] * sc * nv[2]);
    op[3] = f2b(v[3] * sc * nv[3]);
}

// ------------------------------------------------------- generic NT GEMM ----
// C[M,N] = A[M,K] * B[N,K]^T, bf16 in, fp32 acc. lda = ldb = K.
// MODE 0: outB = bf16(acc)                        (xz)
// MODE 1: outF = acc (ld 96); n<64 -> outB bf16   (dbc + dt cast)
// MODE 2: outB = bf16(softplus(acc + bias[n]))    (delta)
// MODE 3: outF = acc + resid[m*N+n]  (fp32 out)   (final out + residual)
#define LDK 56  // padded LDS row stride (bf16 elems): 112 B, 16B-aligned, 2-way banks

template <int MODE>
__global__ __launch_bounds__(256)
void gemm_nt(const bf16* __restrict__ Ab, const bf16* __restrict__ Bb,
             int M, int N, int K,
             float* __restrict__ outF, bf16* __restrict__ outB,
             const float* __restrict__ bias, const float* __restrict__ resid) {
    __shared__ short As[128 * LDK];
    __shared__ short Bs[128 * LDK];
    const short* Ap = (const short*)Ab;
    const short* Bp = (const short*)Bb;

    int t = threadIdx.x;
    int mBase = blockIdx.y * 128;
    int nBase = blockIdx.x * 128;
    int lane = t & 63, wid = t >> 6;
    int wm = (wid >> 1) * 64, wn = (wid & 1) * 64;
    int lr = lane & 15, quad = lane >> 4;

    float4v acc[4][4] = {};

    for (int kt = 0; kt < K; kt += 32) {
        #pragma unroll
        for (int it = 0; it < 2; ++it) {
            int cidx = t + it * 256;        // 0..511
            int row  = cidx >> 2;           // 0..127
            int k8   = (cidx & 3) * 8;      // 0,8,16,24
            short8 av = {0,0,0,0,0,0,0,0};
            short8 bv = {0,0,0,0,0,0,0,0};
            int gm = mBase + row;
            int gn = nBase + row;
            if (gm < M) av = *(const short8*)(Ap + (size_t)gm * K + kt + k8);
            if (gn < N) bv = *(const short8*)(Bp + (size_t)gn * K + kt + k8);
            *(short8*)&As[row * LDK + k8] = av;
            *(short8*)&Bs[row * LDK + k8] = bv;
        }
        __syncthreads();
        short8 af[4], bfr[4];
        #pragma unroll
        for (int i = 0; i < 4; ++i)
            af[i] = *(const short8*)&As[(wm + i * 16 + lr) * LDK + quad * 8];
        #pragma unroll
        for (int j = 0; j < 4; ++j)
            bfr[j] = *(const short8*)&Bs[(wn + j * 16 + lr) * LDK + quad * 8];
        #pragma unroll
        for (int i = 0; i < 4; ++i)
            #pragma unroll
            for (int j = 0; j < 4; ++j)
                acc[i][j] = __builtin_amdgcn_mfma_f32_16x16x32_bf16(af[i], bfr[j], acc[i][j], 0, 0, 0);
        __syncthreads();
    }

    // epilogue: D[row = quad*4+reg][col = lane&15] within each 16x16 tile
    #pragma unroll
    for (int i = 0; i < 4; ++i) {
        #pragma unroll
        for (int j = 0; j < 4; ++j) {
            #pragma unroll
            for (int r = 0; r < 4; ++r) {
                int gm = mBase + wm + i * 16 + quad * 4 + r;
                int gn = nBase + wn + j * 16 + lr;
                if (gm < M && gn < N) {
                    float v = acc[i][j][r];
                    if (MODE == 0) {
                        outB[(size_t)gm * N + gn] = f2b(v);
                    } else if (MODE == 1) {
                        outF[(size_t)gm * N + gn] = v;
                        if (gn < DT_RANK) outB[(size_t)gm * DT_RANK + gn] = f2b(v);
                    } else if (MODE == 2) {
                        v += bias[gn];
                        v = (v > 20.0f) ? v : log1pf(__expf(v));
                        outB[(size_t)gm * N + gn] = f2b(v);
                    } else { // MODE 3
                        outF[(size_t)gm * N + gn] = v + resid[(size_t)gm * N + gn];
                    }
                }
            }
        }
    }
}

// ---------------------------------------------- depthwise causal conv+SiLU ----
__global__ void conv_kernel(const bf16* __restrict__ xz, const float* __restrict__ cw,
                            const float* __restrict__ cb, bf16* __restrict__ xsb) {
    int idx = blockIdx.x * 256 + threadIdx.x;   // over LSEQ*D_INNER
    int c = idx & (D_INNER - 1);
    int l = idx >> 11;
    float w0 = cw[c * 4 + 0];
    float w1 = cw[c * 4 + 1];
    float w2 = cw[c * 4 + 2];
    float w3 = cw[c * 4 + 3];
    float acc = cb[c];
    const bf16* col = xz + c;                   // xc = xz[:, :2048], row stride 4096
    if (l >= 3) acc += b2f(col[(size_t)(l - 3) * (2 * D_INNER)]) * w0;
    if (l >= 2) acc += b2f(col[(size_t)(l - 2) * (2 * D_INNER)]) * w1;
    if (l >= 1) acc += b2f(col[(size_t)(l - 1) * (2 * D_INNER)]) * w2;
    acc += b2f(col[(size_t)l * (2 * D_INNER)]) * w3;
    float s = acc * (1.0f / (1.0f + __expf(-acc)));   // SiLU
    xsb[idx] = f2b(s);
}

// ----------------------------------------------- chunked selective scan -----
// thread t -> (d = blk.x*16 + (t>>4), n = t&15); chunk = blk.y.
// PASS 0: local scan from h=0, emit P (decay product) and S (local end state).
// PASS 1: re-scan seeded with Hinit, emit gated output yg.
template <int PASS>
__global__ __launch_bounds__(256)
void scan_chunk(const bf16* __restrict__ delta, const bf16* __restrict__ xsb,
                const float* __restrict__ dbc, const bf16* __restrict__ xz,
                const float* __restrict__ A_log, const float* __restrict__ Dw,
                const float* __restrict__ Hinit,
                float* __restrict__ P, float* __restrict__ S,
                bf16* __restrict__ yg) {
    int t = threadIdx.x;
    int n = t & 15, dl = t >> 4;
    int d = blockIdx.x * 16 + dl;
    int c = blockIdx.y;
    int l0 = c * CHUNK;
    int dn = d * D_STATE + n;

    float A = -__expf(A_log[dn]);
    float h, prod = 1.0f, Dd = 0.0f;
    if (PASS == 0) h = 0.0f;
    else { h = Hinit[(size_t)c * DN + dn]; Dd = Dw[d]; }

    for (int i = 0; i < CHUNK; ++i) {
        int l = l0 + i;
        float dv = b2f(delta[(size_t)l * D_INNER + d]);
        float xv = b2f(xsb[(size_t)l * D_INNER + d]);
        float Bv = dbc[(size_t)l * 96 + DT_RANK + n];
        float a = __expf(dv * A);
        h = a * h + dv * Bv * xv;
        if (PASS == 0) {
            prod *= a;
        } else {
            float Cv = dbc[(size_t)l * 96 + DT_RANK + D_STATE + n];
            float p = h * Cv;
            p += __shfl_xor(p, 1);
            p += __shfl_xor(p, 2);
            p += __shfl_xor(p, 4);
            p += __shfl_xor(p, 8);
            if (n == 0) {
                float r = b2f(xz[(size_t)l * (2 * D_INNER) + D_INNER + d]);  // res branch
                float y = p + xv * Dd;
                float g = r * (1.0f / (1.0f + __expf(-r)));                  // silu(res)
                yg[(size_t)l * D_INNER + d] = f2b(y * g);
            }
        }
    }
    if (PASS == 0) {
        P[(size_t)c * DN + dn] = prod;
        S[(size_t)c * DN + dn] = h;
    }
}

// Sequential compose over chunks: h_init[c+1] = P[c]*h_init[c] + S[c].
__global__ __launch_bounds__(256)
void scan_mid(const float* __restrict__ P, const float* __restrict__ S,
              float* __restrict__ Hinit) {
    int idx = blockIdx.x * 256 + threadIdx.x;   // over DN
    float p[NCHUNK], s[NCHUNK];
    #pragma unroll
    for (int c = 0; c < NCHUNK; ++c) {
        p[c] = P[(size_t)c * DN + idx];
        s[c] = S[(size_t)c * DN + idx];
    }
    float h = 0.0f;
    #pragma unroll
    for (int c = 0; c < NCHUNK; ++c) {
        Hinit[(size_t)c * DN + idx] = h;
        h = p[c] * h + s[c];
    }
}

// -------------------------------------------------------------- launcher ----
extern "C" void kernel_launch(void* const* d_in, const int* in_sizes, int n_in,
                              void* d_out, int out_size, void* d_ws, size_t ws_size,
                              hipStream_t stream) {
    const float* x       = (const float*)d_in[0];
    const float* W_in    = (const float*)d_in[1];
    const float* conv_w  = (const float*)d_in[2];
    const float* conv_b  = (const float*)d_in[3];
    const float* W_xproj = (const float*)d_in[4];
    const float* W_dt    = (const float*)d_in[5];
    const float* b_dt    = (const float*)d_in[6];
    const float* A_log   = (const float*)d_in[7];
    const float* Dw      = (const float*)d_in[8];
    const float* W_out   = (const float*)d_in[9];
    const float* norm_w  = (const float*)d_in[10];

    char* w = (char*)d_ws;
    bf16* W_in_b    = (bf16*)w; w += (size_t)2 * D_INNER * D_MODEL * 2;     // 8 MB
    bf16* W_out_b   = (bf16*)w; w += (size_t)D_MODEL * D_INNER * 2;         // 4 MB
    bf16* W_xproj_b = (bf16*)w; w += (size_t)96 * D_INNER * 2;              // 384 KB
    bf16* W_dt_b    = (bf16*)w; w += (size_t)D_INNER * DT_RANK * 2;         // 256 KB
    bf16* xn        = (bf16*)w; w += (size_t)LSEQ * D_MODEL * 2;            // 4 MB
    bf16* xz        = (bf16*)w; w += (size_t)LSEQ * 2 * D_INNER * 2;        // 16 MB
    bf16* xsb       = (bf16*)w; w += (size_t)LSEQ * D_INNER * 2;            // 8 MB
    float* dbc      = (float*)w; w += (size_t)LSEQ * 96 * 4;                // 768 KB
    bf16* dtb       = (bf16*)w; w += (size_t)LSEQ * DT_RANK * 2;            // 256 KB
    bf16* delta     = (bf16*)w; w += (size_t)LSEQ * D_INNER * 2;            // 8 MB
    bf16* yg        = (bf16*)w; w += (size_t)LSEQ * D_INNER * 2;            // 8 MB
    float* Pbuf     = (float*)w; w += (size_t)NCHUNK * DN * 4;              // 4 MB
    float* Sbuf     = (float*)w; w += (size_t)NCHUNK * DN * 4;              // 4 MB
    float* Hinit    = (float*)w; w += (size_t)NCHUNK * DN * 4;              // 4 MB

    cast4_kernel<<<(2 * D_INNER * D_MODEL / 4 + 255) / 256, 256, 0, stream>>>(W_in, W_in_b, 2 * D_INNER * D_MODEL / 4);
    cast4_kernel<<<(D_MODEL * D_INNER / 4 + 255) / 256, 256, 0, stream>>>(W_out, W_out_b, D_MODEL * D_INNER / 4);
    cast4_kernel<<<(96 * D_INNER / 4 + 255) / 256, 256, 0, stream>>>(W_xproj, W_xproj_b, 96 * D_INNER / 4);
    cast4_kernel<<<(D_INNER * DT_RANK / 4 + 255) / 256, 256, 0, stream>>>(W_dt, W_dt_b, D_INNER * DT_RANK / 4);

    rms_kernel<<<LSEQ, 256, 0, stream>>>(x, norm_w, xn);

    gemm_nt<0><<<dim3(4096 / 128, 2048 / 128), 256, 0, stream>>>(
        xn, W_in_b, 2048, 4096, 1024, nullptr, xz, nullptr, nullptr);

    conv_kernel<<<(LSEQ * D_INNER) / 256, 256, 0, stream>>>(xz, conv_w, conv_b, xsb);

    gemm_nt<1><<<dim3(1, 2048 / 128), 256, 0, stream>>>(
        xsb, W_xproj_b, 2048, 96, 2048, dbc, dtb, nullptr, nullptr);

    gemm_nt<2><<<dim3(2048 / 128, 2048 / 128), 256, 0, stream>>>(
        dtb, W_dt_b, 2048, 2048, 64, nullptr, delta, b_dt, nullptr);

    dim3 sgrid(D_INNER / 16, NCHUNK);
    scan_chunk<0><<<sgrid, 256, 0, stream>>>(delta, xsb, dbc, xz, A_log, Dw,
                                             nullptr, Pbuf, Sbuf, nullptr);
    scan_mid<<<DN / 256, 256, 0, stream>>>(Pbuf, Sbuf, Hinit);
    scan_chunk<1><<<sgrid, 256, 0, stream>>>(delta, xsb, dbc, xz, A_log, Dw,
                                             Hinit, nullptr, nullptr, yg);

    gemm_nt<3><<<dim3(1024 / 128, 2048 / 128), 256, 0, stream>>>(
        yg, W_out_b, 2048, 1024, 2048, (float*)d_out, nullptr, nullptr, x);
}

// Round 4
// 303.754 us; speedup vs baseline: 6.0581x; 1.4818x over previous
//
#include <hip/hip_runtime.h>
#include <hip/hip_bf16.h>

#define D_MODEL 1024
#define D_INNER 2048
#define DT_RANK 64
#define D_STATE 16
#define LSEQ    2048
#define CHUNK   32
#define NCHUNK  (LSEQ / CHUNK)       // 64
#define DN      (D_INNER * D_STATE)  // 32768

typedef __attribute__((ext_vector_type(8))) short  short8;
typedef __attribute__((ext_vector_type(4))) float  float4v;
typedef __hip_bfloat16 bf16;

static __device__ __forceinline__ float b2f(bf16 v) { return __bfloat162float(v); }
static __device__ __forceinline__ bf16  f2b(float v) { return __float2bfloat16(v); }

#define GLOAD_LDS16(g, l)                                                          \
    __builtin_amdgcn_global_load_lds((const __attribute__((address_space(1))) void*)(g), \
                                     (__attribute__((address_space(3))) void*)(l), 16, 0, 0)

// ----------------------------------------------------------- fp32 -> bf16 ----
__global__ void cast4_kernel(const float* __restrict__ in, bf16* __restrict__ out, int n4) {
    int i = blockIdx.x * 256 + threadIdx.x;
    if (i < n4) {
        float4v v = ((const float4v*)in)[i];
        bf16* o = out + i * 4;
        o[0] = f2b(v[0]); o[1] = f2b(v[1]); o[2] = f2b(v[2]); o[3] = f2b(v[3]);
    }
}

// ---------------------------------------------------------------- RMSNorm ----
__global__ void rms_kernel(const float* __restrict__ x, const float* __restrict__ nw,
                           bf16* __restrict__ xn) {
    int l = blockIdx.x, t = threadIdx.x;
    float4v v = ((const float4v*)(x + (size_t)l * D_MODEL))[t];
    float ssq = v[0]*v[0] + v[1]*v[1] + v[2]*v[2] + v[3]*v[3];
    for (int o = 32; o > 0; o >>= 1) ssq += __shfl_down(ssq, o);
    __shared__ float part[4];
    int lane = t & 63, wid = t >> 6;
    if (lane == 0) part[wid] = ssq;
    __syncthreads();
    float tot = part[0] + part[1] + part[2] + part[3];
    float sc = rsqrtf(tot * (1.0f / D_MODEL) + 1e-5f);
    float4v nv = ((const float4v*)nw)[t];
    bf16* op = xn + (size_t)l * D_MODEL + t * 4;
    op[0] = f2b(v[0] * sc * nv[0]);
    op[1] = f2b(v[1] * sc * nv[1]);
    op[2] = f2b(v[2] * sc * nv[2]);
    op[3] = f2b(v[3] * sc * nv[3]);
}

// ----------------------------- fast NT GEMM (dims multiples of 128, K%32==0) --
// C[M,N] = A[M,K]*B[N,K]^T. global_load_lds staging, unpadded 128x32 tiles.
// MODE 0: outB = bf16(acc)                      (xz)
// MODE 2: outB = bf16(softplus(acc+bias[n]))    (delta)
// MODE 3: outF = acc + resid                    (final out)
template <int MODE>
__global__ __launch_bounds__(256)
void gemm_fast(const bf16* __restrict__ Ab, const bf16* __restrict__ Bb,
               int M, int N, int K,
               float* __restrict__ outF, bf16* __restrict__ outB,
               const float* __restrict__ bias, const float* __restrict__ resid) {
    __shared__ short As[128 * 32];
    __shared__ short Bs[128 * 32];
    const short* Ap = (const short*)Ab;
    const short* Bp = (const short*)Bb;

    int t = threadIdx.x;
    int lane = t & 63, wid = t >> 6;
    int mBase = blockIdx.y * 128, nBase = blockIdx.x * 128;
    int wm = (wid >> 1) * 64, wn = (wid & 1) * 64;
    int lr = lane & 15, quad = lane >> 4;

    // staging: wave wid covers tile rows [32*wid, 32*wid+32); each instr = 16 rows.
    // lane j -> row r0 + (j>>2), 16B chunk (j&3). LDS layout row-major 32 shorts/row.
    int srow = 32 * wid + (lane >> 2);
    const short* gA0 = Ap + (size_t)(mBase + srow) * K + (lane & 3) * 8;
    const short* gA1 = gA0 + (size_t)16 * K;
    const short* gB0 = Bp + (size_t)(nBase + srow) * K + (lane & 3) * 8;
    const short* gB1 = gB0 + (size_t)16 * K;
    short* lA0 = &As[(32 * wid) * 32];
    short* lA1 = &As[(32 * wid + 16) * 32];
    short* lB0 = &Bs[(32 * wid) * 32];
    short* lB1 = &Bs[(32 * wid + 16) * 32];

    float4v acc[4][4] = {};

    for (int kt = 0; kt < K; kt += 32) {
        GLOAD_LDS16(gA0 + kt, lA0);
        GLOAD_LDS16(gA1 + kt, lA1);
        GLOAD_LDS16(gB0 + kt, lB0);
        GLOAD_LDS16(gB1 + kt, lB1);
        __syncthreads();
        short8 af[4], bfr[4];
        #pragma unroll
        for (int i = 0; i < 4; ++i)
            af[i] = *(const short8*)&As[(wm + i * 16 + lr) * 32 + quad * 8];
        #pragma unroll
        for (int j = 0; j < 4; ++j)
            bfr[j] = *(const short8*)&Bs[(wn + j * 16 + lr) * 32 + quad * 8];
        #pragma unroll
        for (int i = 0; i < 4; ++i)
            #pragma unroll
            for (int j = 0; j < 4; ++j)
                acc[i][j] = __builtin_amdgcn_mfma_f32_16x16x32_bf16(af[i], bfr[j], acc[i][j], 0, 0, 0);
        __syncthreads();
    }

    #pragma unroll
    for (int i = 0; i < 4; ++i) {
        #pragma unroll
        for (int j = 0; j < 4; ++j) {
            #pragma unroll
            for (int r = 0; r < 4; ++r) {
                int gm = mBase + wm + i * 16 + quad * 4 + r;
                int gn = nBase + wn + j * 16 + lr;
                float v = acc[i][j][r];
                if (MODE == 0) {
                    outB[(size_t)gm * N + gn] = f2b(v);
                } else if (MODE == 2) {
                    v += bias[gn];
                    v = (v > 20.0f) ? v : log1pf(__expf(v));
                    outB[(size_t)gm * N + gn] = f2b(v);
                } else {
                    outF[(size_t)gm * N + gn] = v + resid[(size_t)gm * N + gn];
                }
            }
        }
    }
}

// ------------------------------- split-K GEMM for x_proj (M=2048,N=96,K=2048) --
#define LDK 56
__global__ __launch_bounds__(256)
void gemm_splitk(const bf16* __restrict__ Ab, const bf16* __restrict__ Bb,
                 float* __restrict__ outF) {
    const int M = 2048, N = 96, K = 2048, KCH = 128;
    __shared__ short As[128 * LDK];
    __shared__ short Bs[128 * LDK];
    const short* Ap = (const short*)Ab;
    const short* Bp = (const short*)Bb;

    int t = threadIdx.x;
    int mBase = blockIdx.y * 128;
    int k0 = blockIdx.z * KCH;
    int lane = t & 63, wid = t >> 6;
    int wm = (wid >> 1) * 64, wn = (wid & 1) * 64;
    int lr = lane & 15, quad = lane >> 4;

    float4v acc[4][4] = {};

    for (int kt = k0; kt < k0 + KCH; kt += 32) {
        #pragma unroll
        for (int it = 0; it < 2; ++it) {
            int cidx = t + it * 256;
            int row  = cidx >> 2;
            int k8   = (cidx & 3) * 8;
            short8 av = *(const short8*)(Ap + (size_t)(mBase + row) * K + kt + k8);
            short8 bv = {0,0,0,0,0,0,0,0};
            if (row < N) bv = *(const short8*)(Bp + (size_t)row * K + kt + k8);
            *(short8*)&As[row * LDK + k8] = av;
            *(short8*)&Bs[row * LDK + k8] = bv;
        }
        __syncthreads();
        short8 af[4], bfr[4];
        #pragma unroll
        for (int i = 0; i < 4; ++i)
            af[i] = *(const short8*)&As[(wm + i * 16 + lr) * LDK + quad * 8];
        #pragma unroll
        for (int j = 0; j < 4; ++j)
            bfr[j] = *(const short8*)&Bs[(wn + j * 16 + lr) * LDK + quad * 8];
        #pragma unroll
        for (int i = 0; i < 4; ++i)
            #pragma unroll
            for (int j = 0; j < 4; ++j)
                acc[i][j] = __builtin_amdgcn_mfma_f32_16x16x32_bf16(af[i], bfr[j], acc[i][j], 0, 0, 0);
        __syncthreads();
    }

    #pragma unroll
    for (int i = 0; i < 4; ++i)
        #pragma unroll
        for (int j = 0; j < 4; ++j)
            #pragma unroll
            for (int r = 0; r < 4; ++r) {
                int gm = mBase + wm + i * 16 + quad * 4 + r;
                int gn = wn + j * 16 + lr;
                if (gn < N) atomicAdd(&outF[(size_t)gm * N + gn], acc[i][j][r]);
            }
}

// dt columns of dbc -> bf16 for gemm2
__global__ void cast_dt(const float* __restrict__ dbc, bf16* __restrict__ dtb) {
    int idx = blockIdx.x * 256 + threadIdx.x;   // over 2048*64
    int m = idx >> 6, j = idx & 63;
    dtb[idx] = f2b(dbc[(size_t)m * 96 + j]);
}

// ---------------------------------------------- depthwise causal conv+SiLU ----
__global__ void conv_kernel(const bf16* __restrict__ xz, const float* __restrict__ cw,
                            const float* __restrict__ cb, bf16* __restrict__ xsb) {
    int idx = blockIdx.x * 256 + threadIdx.x;   // over LSEQ*D_INNER
    int c = idx & (D_INNER - 1);
    int l = idx >> 11;
    float w0 = cw[c * 4 + 0], w1 = cw[c * 4 + 1];
    float w2 = cw[c * 4 + 2], w3 = cw[c * 4 + 3];
    float acc = cb[c];
    const bf16* col = xz + c;
    if (l >= 3) acc += b2f(col[(size_t)(l - 3) * (2 * D_INNER)]) * w0;
    if (l >= 2) acc += b2f(col[(size_t)(l - 2) * (2 * D_INNER)]) * w1;
    if (l >= 1) acc += b2f(col[(size_t)(l - 1) * (2 * D_INNER)]) * w2;
    acc += b2f(col[(size_t)l * (2 * D_INNER)]) * w3;
    float s = acc * (1.0f / (1.0f + __expf(-acc)));
    xsb[idx] = f2b(s);
}

// ------------------------------- chunked selective scan, states in registers --
// thread = (d, chunk): d = blk.x*256 + tid, chunk = blk.y. h[16] in VGPRs.
// PASS 0: from h=0, emit decay products P[c][dn] and end states S[c][dn].
// PASS 1: seeded with Hinit, emit gated output yg.
template <int PASS>
__global__ __launch_bounds__(256)
void scan2(const bf16* __restrict__ delta, const bf16* __restrict__ xsb,
           const float* __restrict__ dbc, const bf16* __restrict__ xz,
           const float* __restrict__ A_log, const float* __restrict__ Dw,
           const float* __restrict__ Hinit,
           float* __restrict__ P, float* __restrict__ S, bf16* __restrict__ yg) {
    __shared__ float bc[CHUNK][32];   // [l][B(16)|C(16)]
    int t = threadIdx.x;
    int d = blockIdx.x * 256 + t;
    int c = blockIdx.y;
    int l0 = c * CHUNK;

    {   // stage B,C for this chunk: 32 rows x 32 floats = 4 KB
        int row = t >> 3, col = (t & 7) * 4;
        *(float4v*)&bc[row][col] = *(const float4v*)&dbc[(size_t)(l0 + row) * 96 + 64 + col];
    }
    __syncthreads();

    float A[16], h[16], pr[16];
    #pragma unroll
    for (int n = 0; n < 16; ++n) A[n] = -__expf(A_log[(size_t)d * 16 + n]);
    if (PASS == 0) {
        #pragma unroll
        for (int n = 0; n < 16; ++n) { h[n] = 0.0f; pr[n] = 1.0f; }
    } else {
        #pragma unroll
        for (int n = 0; n < 16; n += 4)
            *(float4v*)&h[n] = *(const float4v*)&Hinit[(size_t)c * DN + (size_t)d * 16 + n];
    }
    float Dd = (PASS == 1) ? Dw[d] : 0.0f;

    for (int i = 0; i < CHUNK; ++i) {
        int l = l0 + i;
        float dv = b2f(delta[(size_t)l * D_INNER + d]);
        float xv = b2f(xsb[(size_t)l * D_INNER + d]);
        float u = dv * xv;
        float Bv[16];
        #pragma unroll
        for (int n = 0; n < 16; n += 4) *(float4v*)&Bv[n] = *(const float4v*)&bc[i][n];
        #pragma unroll
        for (int n = 0; n < 16; ++n) {
            float a = __expf(dv * A[n]);
            h[n] = fmaf(a, h[n], Bv[n] * u);
            if (PASS == 0) pr[n] *= a;
        }
        if (PASS == 1) {
            float Cv[16];
            #pragma unroll
            for (int n = 0; n < 16; n += 4) *(float4v*)&Cv[n] = *(const float4v*)&bc[i][16 + n];
            float y = xv * Dd;
            #pragma unroll
            for (int n = 0; n < 16; ++n) y = fmaf(h[n], Cv[n], y);
            float r = b2f(xz[(size_t)l * (2 * D_INNER) + D_INNER + d]);
            float g = r * (1.0f / (1.0f + __expf(-r)));
            yg[(size_t)l * D_INNER + d] = f2b(y * g);
        }
    }
    if (PASS == 0) {
        #pragma unroll
        for (int n = 0; n < 16; n += 4) {
            *(float4v*)&P[(size_t)c * DN + (size_t)d * 16 + n] = *(float4v*)&pr[n];
            *(float4v*)&S[(size_t)c * DN + (size_t)d * 16 + n] = *(float4v*)&h[n];
        }
    }
}

// Sequential compose over chunks: h_init[c+1] = P[c]*h_init[c] + S[c].
__global__ __launch_bounds__(256)
void scan_mid(const float* __restrict__ P, const float* __restrict__ S,
              float* __restrict__ Hinit) {
    int idx = blockIdx.x * 256 + threadIdx.x;   // over DN
    float h = 0.0f;
    for (int c0 = 0; c0 < NCHUNK; c0 += 8) {
        float p[8], s[8];
        #pragma unroll
        for (int j = 0; j < 8; ++j) {
            p[j] = P[(size_t)(c0 + j) * DN + idx];
            s[j] = S[(size_t)(c0 + j) * DN + idx];
        }
        #pragma unroll
        for (int j = 0; j < 8; ++j) {
            Hinit[(size_t)(c0 + j) * DN + idx] = h;
            h = fmaf(p[j], h, s[j]);
        }
    }
}

// -------------------------------------------------------------- launcher ----
extern "C" void kernel_launch(void* const* d_in, const int* in_sizes, int n_in,
                              void* d_out, int out_size, void* d_ws, size_t ws_size,
                              hipStream_t stream) {
    const float* x       = (const float*)d_in[0];
    const float* W_in    = (const float*)d_in[1];
    const float* conv_w  = (const float*)d_in[2];
    const float* conv_b  = (const float*)d_in[3];
    const float* W_xproj = (const float*)d_in[4];
    const float* W_dt    = (const float*)d_in[5];
    const float* b_dt    = (const float*)d_in[6];
    const float* A_log   = (const float*)d_in[7];
    const float* Dw      = (const float*)d_in[8];
    const float* W_out   = (const float*)d_in[9];
    const float* norm_w  = (const float*)d_in[10];

    char* w = (char*)d_ws;
    bf16* W_in_b    = (bf16*)w; w += (size_t)2 * D_INNER * D_MODEL * 2;
    bf16* W_out_b   = (bf16*)w; w += (size_t)D_MODEL * D_INNER * 2;
    bf16* W_xproj_b = (bf16*)w; w += (size_t)96 * D_INNER * 2;
    bf16* W_dt_b    = (bf16*)w; w += (size_t)D_INNER * DT_RANK * 2;
    bf16* xn        = (bf16*)w; w += (size_t)LSEQ * D_MODEL * 2;
    bf16* xz        = (bf16*)w; w += (size_t)LSEQ * 2 * D_INNER * 2;
    bf16* xsb       = (bf16*)w; w += (size_t)LSEQ * D_INNER * 2;
    float* dbc      = (float*)w; w += (size_t)LSEQ * 96 * 4;
    bf16* dtb       = (bf16*)w; w += (size_t)LSEQ * DT_RANK * 2;
    bf16* delta     = (bf16*)w; w += (size_t)LSEQ * D_INNER * 2;
    bf16* yg        = (bf16*)w; w += (size_t)LSEQ * D_INNER * 2;
    float* Pbuf     = (float*)w; w += (size_t)NCHUNK * DN * 4;
    float* Sbuf     = (float*)w; w += (size_t)NCHUNK * DN * 4;
    float* Hinit    = (float*)w; w += (size_t)NCHUNK * DN * 4;

    cast4_kernel<<<2 * D_INNER * D_MODEL / 4 / 256, 256, 0, stream>>>(W_in, W_in_b, 2 * D_INNER * D_MODEL / 4);
    cast4_kernel<<<D_MODEL * D_INNER / 4 / 256, 256, 0, stream>>>(W_out, W_out_b, D_MODEL * D_INNER / 4);
    cast4_kernel<<<96 * D_INNER / 4 / 256, 256, 0, stream>>>(W_xproj, W_xproj_b, 96 * D_INNER / 4);
    cast4_kernel<<<D_INNER * DT_RANK / 4 / 256, 256, 0, stream>>>(W_dt, W_dt_b, D_INNER * DT_RANK / 4);

    rms_kernel<<<LSEQ, 256, 0, stream>>>(x, norm_w, xn);

    gemm_fast<0><<<dim3(4096 / 128, 2048 / 128), 256, 0, stream>>>(
        xn, W_in_b, 2048, 4096, 1024, nullptr, xz, nullptr, nullptr);

    conv_kernel<<<(LSEQ * D_INNER) / 256, 256, 0, stream>>>(xz, conv_w, conv_b, xsb);

    hipMemsetAsync(dbc, 0, (size_t)LSEQ * 96 * 4, stream);
    gemm_splitk<<<dim3(1, 16, 16), 256, 0, stream>>>(xsb, W_xproj_b, dbc);
    cast_dt<<<LSEQ * DT_RANK / 256, 256, 0, stream>>>(dbc, dtb);

    gemm_fast<2><<<dim3(2048 / 128, 2048 / 128), 256, 0, stream>>>(
        dtb, W_dt_b, 2048, 2048, 64, nullptr, delta, b_dt, nullptr);

    dim3 sgrid(D_INNER / 256, NCHUNK);
    scan2<0><<<sgrid, 256, 0, stream>>>(delta, xsb, dbc, xz, A_log, Dw,
                                        nullptr, Pbuf, Sbuf, nullptr);
    scan_mid<<<DN / 256, 256, 0, stream>>>(Pbuf, Sbuf, Hinit);
    scan2<1><<<sgrid, 256, 0, stream>>>(delta, xsb, dbc, xz, A_log, Dw,
                                        Hinit, nullptr, nullptr, yg);

    gemm_fast<3><<<dim3(1024 / 128, 2048 / 128), 256, 0, stream>>>(
        yg, W_out_b, 2048, 1024, 2048, (float*)d_out, nullptr, nullptr, x);
}

// Round 5
// 265.754 us; speedup vs baseline: 6.9244x; 1.1430x over previous
//
#include <hip/hip_runtime.h>
#include <hip/hip_bf16.h>

#define D_MODEL 1024
#define D_INNER 2048
#define DT_RANK 64
#define D_STATE 16
#define LSEQ    2048
#define CHUNK   32
#define NCHUNK  (LSEQ / CHUNK)       // 64
#define DN      (D_INNER * D_STATE)  // 32768
#define KSPL_O  4                    // split-K for out-proj
#define KSPL_X  16                   // split-K for x-proj

typedef __attribute__((ext_vector_type(8))) short  short8;
typedef __attribute__((ext_vector_type(4))) float  float4v;
typedef __hip_bfloat16 bf16;

static __device__ __forceinline__ float b2f(bf16 v) { return __bfloat162float(v); }
static __device__ __forceinline__ bf16  f2b(float v) { return __float2bfloat16(v); }

#define GLOAD_LDS16(g, l)                                                          \
    __builtin_amdgcn_global_load_lds((const __attribute__((address_space(1))) void*)(g), \
                                     (__attribute__((address_space(3))) void*)(l), 16, 0, 0)

// --------------------------------------------- fused fp32 -> bf16 weight cast --
#define N1 (2 * D_INNER * D_MODEL)   // W_in
#define N2 (D_MODEL * D_INNER)       // W_out
#define N3 (96 * D_INNER)            // W_xproj
#define N4 (D_INNER * DT_RANK)       // W_dt
__global__ __launch_bounds__(256)
void cast_all(const float* __restrict__ w_in, const float* __restrict__ w_out,
              const float* __restrict__ w_xp, const float* __restrict__ w_dt,
              bf16* __restrict__ o_in, bf16* __restrict__ o_out,
              bf16* __restrict__ o_xp, bf16* __restrict__ o_dt) {
    int i4 = blockIdx.x * 256 + threadIdx.x;
    const float* src; bf16* dst; int base;
    if (i4 < N1 / 4)                { src = w_in;  dst = o_in;  base = 0; }
    else if (i4 < (N1 + N2) / 4)    { src = w_out; dst = o_out; base = N1 / 4; }
    else if (i4 < (N1+N2+N3) / 4)   { src = w_xp;  dst = o_xp;  base = (N1+N2) / 4; }
    else if (i4 < (N1+N2+N3+N4)/4)  { src = w_dt;  dst = o_dt;  base = (N1+N2+N3) / 4; }
    else return;
    int j = i4 - base;
    float4v v = ((const float4v*)src)[j];
    bf16* o = dst + j * 4;
    o[0] = f2b(v[0]); o[1] = f2b(v[1]); o[2] = f2b(v[2]); o[3] = f2b(v[3]);
}

// ---------------------------------------------------------------- RMSNorm ----
__global__ void rms_kernel(const float* __restrict__ x, const float* __restrict__ nw,
                           bf16* __restrict__ xn) {
    int l = blockIdx.x, t = threadIdx.x;
    float4v v = ((const float4v*)(x + (size_t)l * D_MODEL))[t];
    float ssq = v[0]*v[0] + v[1]*v[1] + v[2]*v[2] + v[3]*v[3];
    for (int o = 32; o > 0; o >>= 1) ssq += __shfl_down(ssq, o);
    __shared__ float part[4];
    int lane = t & 63, wid = t >> 6;
    if (lane == 0) part[wid] = ssq;
    __syncthreads();
    float tot = part[0] + part[1] + part[2] + part[3];
    float sc = rsqrtf(tot * (1.0f / D_MODEL) + 1e-5f);
    float4v nv = ((const float4v*)nw)[t];
    bf16* op = xn + (size_t)l * D_MODEL + t * 4;
    op[0] = f2b(v[0] * sc * nv[0]);
    op[1] = f2b(v[1] * sc * nv[1]);
    op[2] = f2b(v[2] * sc * nv[2]);
    op[3] = f2b(v[3] * sc * nv[3]);
}

// ----------------------------- fast NT GEMM (tiles 128x128, K%32==0) ----------
// global_load_lds staging, XOR-swizzled LDS (kills b128 phase conflicts),
// single-barrier double-buffered K-loop (prefetch overlaps MFMA).
// MODE 0: outB = bf16(acc)                       (xz)
// MODE 2: outB = bf16(softplus(acc+bias[n]))     (delta)
// MODE 4: outF[z-slice] = acc                    (split-K partials)
template <int MODE>
__global__ __launch_bounds__(256)
void gemm_fast(const bf16* __restrict__ Ab, const bf16* __restrict__ Bb,
               int M, int N, int K, int kLen,
               float* __restrict__ outF, bf16* __restrict__ outB,
               const float* __restrict__ bias) {
    __shared__ short As[2][128 * 32];
    __shared__ short Bs[2][128 * 32];
    const short* Ap = (const short*)Ab;
    const short* Bp = (const short*)Bb;

    int t = threadIdx.x;
    int lane = t & 63, wid = t >> 6;
    int mBase = blockIdx.y * 128, nBase = blockIdx.x * 128;
    int kBase = blockIdx.z * kLen;
    int wm = (wid >> 1) * 64, wn = (wid & 1) * 64;
    int lr = lane & 15, quad = lane >> 4;

    // staging: wave wid covers tile rows [32*wid, 32*wid+32); 16 rows/instr.
    // lane j -> LDS row (j>>2), chunk (j&3); fetches global chunk (j&3)^((j>>3)&3)
    // so that LDS(r,c) holds global chunk c^((r>>1)&3)  [XOR swizzle].
    int srow = 32 * wid + (lane >> 2);
    int cg = (lane & 3) ^ ((lane >> 3) & 3);
    const short* gA0 = Ap + (size_t)(mBase + srow) * K + cg * 8;
    const short* gA1 = gA0 + (size_t)16 * K;
    const short* gB0 = Bp + (size_t)(nBase + srow) * K + cg * 8;
    const short* gB1 = gB0 + (size_t)16 * K;

    float4v acc[4][4] = {};
    int sw = (lr >> 1) & 3;   // read-side swizzle

    // prologue: stage first tile into buf 0
    GLOAD_LDS16(gA0 + kBase, &As[0][(32 * wid) * 32]);
    GLOAD_LDS16(gA1 + kBase, &As[0][(32 * wid + 16) * 32]);
    GLOAD_LDS16(gB0 + kBase, &Bs[0][(32 * wid) * 32]);
    GLOAD_LDS16(gB1 + kBase, &Bs[0][(32 * wid + 16) * 32]);

    int p = 0;
    for (int kt = kBase; kt < kBase + kLen; kt += 32, p ^= 1) {
        __syncthreads();   // drains buf[p] loads; guards buf[p^1] overwrite
        if (kt + 32 < kBase + kLen) {
            int kn = kt + 32, q = p ^ 1;
            GLOAD_LDS16(gA0 + kn, &As[q][(32 * wid) * 32]);
            GLOAD_LDS16(gA1 + kn, &As[q][(32 * wid + 16) * 32]);
            GLOAD_LDS16(gB0 + kn, &Bs[q][(32 * wid) * 32]);
            GLOAD_LDS16(gB1 + kn, &Bs[q][(32 * wid + 16) * 32]);
        }
        short8 af[4], bfr[4];
        #pragma unroll
        for (int i = 0; i < 4; ++i)
            af[i] = *(const short8*)&As[p][(wm + i * 16 + lr) * 32 + ((quad ^ sw) * 8)];
        #pragma unroll
        for (int j = 0; j < 4; ++j)
            bfr[j] = *(const short8*)&Bs[p][(wn + j * 16 + lr) * 32 + ((quad ^ sw) * 8)];
        #pragma unroll
        for (int i = 0; i < 4; ++i)
            #pragma unroll
            for (int j = 0; j < 4; ++j)
                acc[i][j] = __builtin_amdgcn_mfma_f32_16x16x32_bf16(af[i], bfr[j], acc[i][j], 0, 0, 0);
    }

    #pragma unroll
    for (int i = 0; i < 4; ++i) {
        #pragma unroll
        for (int j = 0; j < 4; ++j) {
            #pragma unroll
            for (int r = 0; r < 4; ++r) {
                int gm = mBase + wm + i * 16 + quad * 4 + r;
                int gn = nBase + wn + j * 16 + lr;
                float v = acc[i][j][r];
                if (MODE == 0) {
                    outB[(size_t)gm * N + gn] = f2b(v);
                } else if (MODE == 2) {
                    v += bias[gn];
                    v = (v > 20.0f) ? v : log1pf(__expf(v));
                    outB[(size_t)gm * N + gn] = f2b(v);
                } else {  // MODE 4: split-K partials
                    outF[((size_t)blockIdx.z * M + gm) * N + gn] = v;
                }
            }
        }
    }
}

// --------------- x_proj reduce: dbc = sum_z part, + dt bf16 cast (fused) ------
__global__ __launch_bounds__(128)
void reduce_xproj(const float* __restrict__ part, float* __restrict__ dbc,
                  bf16* __restrict__ dtb) {
    int m = blockIdx.x, j = threadIdx.x;
    if (j >= 96) return;
    float v = 0.0f;
    #pragma unroll
    for (int z = 0; z < KSPL_X; ++z)
        v += part[((size_t)z * LSEQ + m) * 128 + j];
    dbc[(size_t)m * 96 + j] = v;
    if (j < DT_RANK) dtb[(size_t)m * DT_RANK + j] = f2b(v);
}

// --------------- out reduce: d_out = sum_z part + x (residual fused) ----------
__global__ __launch_bounds__(256)
void reduce_out(const float* __restrict__ part, const float* __restrict__ x,
                float* __restrict__ out) {
    int i = blockIdx.x * 256 + threadIdx.x;   // float4 over M*N/4
    const int MN4 = LSEQ * D_MODEL / 4;
    float4v a = ((const float4v*)part)[i];
    #pragma unroll
    for (int z = 1; z < KSPL_O; ++z) {
        float4v b = ((const float4v*)part)[(size_t)z * MN4 + i];
        a[0] += b[0]; a[1] += b[1]; a[2] += b[2]; a[3] += b[3];
    }
    float4v xv = ((const float4v*)x)[i];
    a[0] += xv[0]; a[1] += xv[1]; a[2] += xv[2]; a[3] += xv[3];
    ((float4v*)out)[i] = a;
}

// ---------------------------------------------- depthwise causal conv+SiLU ----
__global__ void conv_kernel(const bf16* __restrict__ xz, const float* __restrict__ cw,
                            const float* __restrict__ cb, bf16* __restrict__ xsb) {
    int idx = blockIdx.x * 256 + threadIdx.x;   // over LSEQ*D_INNER
    int c = idx & (D_INNER - 1);
    int l = idx >> 11;
    float w0 = cw[c * 4 + 0], w1 = cw[c * 4 + 1];
    float w2 = cw[c * 4 + 2], w3 = cw[c * 4 + 3];
    float acc = cb[c];
    const bf16* col = xz + c;
    if (l >= 3) acc += b2f(col[(size_t)(l - 3) * (2 * D_INNER)]) * w0;
    if (l >= 2) acc += b2f(col[(size_t)(l - 2) * (2 * D_INNER)]) * w1;
    if (l >= 1) acc += b2f(col[(size_t)(l - 1) * (2 * D_INNER)]) * w2;
    acc += b2f(col[(size_t)l * (2 * D_INNER)]) * w3;
    float s = acc * (1.0f / (1.0f + __expf(-acc)));
    xsb[idx] = f2b(s);
}

// ------------------------------- chunked selective scan, states in registers --
template <int PASS>
__global__ __launch_bounds__(256)
void scan2(const bf16* __restrict__ delta, const bf16* __restrict__ xsb,
           const float* __restrict__ dbc, const bf16* __restrict__ xz,
           const float* __restrict__ A_log, const float* __restrict__ Dw,
           const float* __restrict__ Hinit,
           float* __restrict__ P, float* __restrict__ S, bf16* __restrict__ yg) {
    __shared__ float bc[CHUNK][32];   // [l][B(16)|C(16)]
    int t = threadIdx.x;
    int d = blockIdx.x * 256 + t;
    int c = blockIdx.y;
    int l0 = c * CHUNK;

    {   // stage B,C for this chunk: 32 rows x 32 floats = 4 KB
        int row = t >> 3, col = (t & 7) * 4;
        *(float4v*)&bc[row][col] = *(const float4v*)&dbc[(size_t)(l0 + row) * 96 + 64 + col];
    }
    __syncthreads();

    float A[16], h[16], pr[16];
    #pragma unroll
    for (int n = 0; n < 16; ++n) A[n] = -__expf(A_log[(size_t)d * 16 + n]);
    if (PASS == 0) {
        #pragma unroll
        for (int n = 0; n < 16; ++n) { h[n] = 0.0f; pr[n] = 1.0f; }
    } else {
        #pragma unroll
        for (int n = 0; n < 16; n += 4)
            *(float4v*)&h[n] = *(const float4v*)&Hinit[(size_t)c * DN + (size_t)d * 16 + n];
    }
    float Dd = (PASS == 1) ? Dw[d] : 0.0f;

    for (int i = 0; i < CHUNK; ++i) {
        int l = l0 + i;
        float dv = b2f(delta[(size_t)l * D_INNER + d]);
        float xv = b2f(xsb[(size_t)l * D_INNER + d]);
        float u = dv * xv;
        float Bv[16];
        #pragma unroll
        for (int n = 0; n < 16; n += 4) *(float4v*)&Bv[n] = *(const float4v*)&bc[i][n];
        #pragma unroll
        for (int n = 0; n < 16; ++n) {
            float a = __expf(dv * A[n]);
            h[n] = fmaf(a, h[n], Bv[n] * u);
            if (PASS == 0) pr[n] *= a;
        }
        if (PASS == 1) {
            float Cv[16];
            #pragma unroll
            for (int n = 0; n < 16; n += 4) *(float4v*)&Cv[n] = *(const float4v*)&bc[i][16 + n];
            float y = xv * Dd;
            #pragma unroll
            for (int n = 0; n < 16; ++n) y = fmaf(h[n], Cv[n], y);
            float r = b2f(xz[(size_t)l * (2 * D_INNER) + D_INNER + d]);
            float g = r * (1.0f / (1.0f + __expf(-r)));
            yg[(size_t)l * D_INNER + d] = f2b(y * g);
        }
    }
    if (PASS == 0) {
        #pragma unroll
        for (int n = 0; n < 16; n += 4) {
            *(float4v*)&P[(size_t)c * DN + (size_t)d * 16 + n] = *(float4v*)&pr[n];
            *(float4v*)&S[(size_t)c * DN + (size_t)d * 16 + n] = *(float4v*)&h[n];
        }
    }
}

// Sequential compose over chunks: h_init[c+1] = P[c]*h_init[c] + S[c].
__global__ __launch_bounds__(256)
void scan_mid(const float* __restrict__ P, const float* __restrict__ S,
              float* __restrict__ Hinit) {
    int idx = blockIdx.x * 256 + threadIdx.x;   // over DN
    float h = 0.0f;
    for (int c0 = 0; c0 < NCHUNK; c0 += 8) {
        float p[8], s[8];
        #pragma unroll
        for (int j = 0; j < 8; ++j) {
            p[j] = P[(size_t)(c0 + j) * DN + idx];
            s[j] = S[(size_t)(c0 + j) * DN + idx];
        }
        #pragma unroll
        for (int j = 0; j < 8; ++j) {
            Hinit[(size_t)(c0 + j) * DN + idx] = h;
            h = fmaf(p[j], h, s[j]);
        }
    }
}

// -------------------------------------------------------------- launcher ----
extern "C" void kernel_launch(void* const* d_in, const int* in_sizes, int n_in,
                              void* d_out, int out_size, void* d_ws, size_t ws_size,
                              hipStream_t stream) {
    const float* x       = (const float*)d_in[0];
    const float* W_in    = (const float*)d_in[1];
    const float* conv_w  = (const float*)d_in[2];
    const float* conv_b  = (const float*)d_in[3];
    const float* W_xproj = (const float*)d_in[4];
    const float* W_dt    = (const float*)d_in[5];
    const float* b_dt    = (const float*)d_in[6];
    const float* A_log   = (const float*)d_in[7];
    const float* Dw      = (const float*)d_in[8];
    const float* W_out   = (const float*)d_in[9];
    const float* norm_w  = (const float*)d_in[10];

    char* w = (char*)d_ws;
    bf16* W_in_b    = (bf16*)w; w += (size_t)2 * D_INNER * D_MODEL * 2;   // 8 MB
    bf16* W_out_b   = (bf16*)w; w += (size_t)D_MODEL * D_INNER * 2;       // 4 MB
    bf16* W_xproj_b = (bf16*)w; w += (size_t)128 * D_INNER * 2;           // 512 KB (96 used; 128-row tile reads pad)
    bf16* W_dt_b    = (bf16*)w; w += (size_t)D_INNER * DT_RANK * 2;       // 256 KB
    // region reused by out-proj partials after scan pass 1:
    char* reuse0 = w;
    bf16* xn        = (bf16*)w; w += (size_t)LSEQ * D_MODEL * 2;          // 4 MB
    bf16* xz        = (bf16*)w; w += (size_t)LSEQ * 2 * D_INNER * 2;      // 16 MB
    bf16* xsb       = (bf16*)w; w += (size_t)LSEQ * D_INNER * 2;          // 8 MB
    bf16* delta     = (bf16*)w; w += (size_t)LSEQ * D_INNER * 2;          // 8 MB  (36 MB reuse pool)
    float* dbc      = (float*)w; w += (size_t)LSEQ * 96 * 4;              // 768 KB
    bf16* dtb       = (bf16*)w; w += (size_t)LSEQ * DT_RANK * 2;          // 256 KB
    bf16* yg        = (bf16*)w; w += (size_t)LSEQ * D_INNER * 2;          // 8 MB
    float* Pbuf     = (float*)w; w += (size_t)NCHUNK * DN * 4;            // 8 MB
    float* Sbuf     = (float*)w; w += (size_t)NCHUNK * DN * 4;            // 8 MB
    float* Hinit    = (float*)w; w += (size_t)NCHUNK * DN * 4;            // 8 MB
    float* xp_part  = (float*)w; w += (size_t)KSPL_X * LSEQ * 128 * 4;    // 16 MB
    float* out_part = (float*)reuse0;   // 32 MB, aliases xn/xz/xsb/delta (dead by then)

    cast_all<<<(N1 + N2 + N3 + N4) / 4 / 256, 256, 0, stream>>>(
        W_in, W_out, W_xproj, W_dt, W_in_b, W_out_b, W_xproj_b, W_dt_b);

    rms_kernel<<<LSEQ, 256, 0, stream>>>(x, norm_w, xn);

    // in_proj: (2048 x 4096) = xn (2048x1024) * W_in^T
    gemm_fast<0><<<dim3(4096 / 128, 2048 / 128, 1), 256, 0, stream>>>(
        xn, W_in_b, 2048, 4096, 1024, 1024, nullptr, xz, nullptr);

    conv_kernel<<<(LSEQ * D_INNER) / 256, 256, 0, stream>>>(xz, conv_w, conv_b, xsb);

    // x_proj: (2048 x 96) = xsb (2048x2048) * W_xproj^T, split-K=16, N padded to 128
    gemm_fast<4><<<dim3(1, 2048 / 128, KSPL_X), 256, 0, stream>>>(
        xsb, W_xproj_b, 2048, 128, 2048, 2048 / KSPL_X, xp_part, nullptr, nullptr);
    reduce_xproj<<<LSEQ, 128, 0, stream>>>(xp_part, dbc, dtb);

    // delta: (2048 x 2048) = dtb (2048x64) * W_dt^T, softplus+bias epilogue
    gemm_fast<2><<<dim3(2048 / 128, 2048 / 128, 1), 256, 0, stream>>>(
        dtb, W_dt_b, 2048, 2048, 64, 64, nullptr, delta, b_dt);

    dim3 sgrid(D_INNER / 256, NCHUNK);
    scan2<0><<<sgrid, 256, 0, stream>>>(delta, xsb, dbc, xz, A_log, Dw,
                                        nullptr, Pbuf, Sbuf, nullptr);
    scan_mid<<<DN / 256, 256, 0, stream>>>(Pbuf, Sbuf, Hinit);
    scan2<1><<<sgrid, 256, 0, stream>>>(delta, xsb, dbc, xz, A_log, Dw,
                                        Hinit, nullptr, nullptr, yg);

    // out_proj: (2048 x 1024) = yg (2048x2048) * W_out^T, split-K=4
    gemm_fast<4><<<dim3(1024 / 128, 2048 / 128, KSPL_O), 256, 0, stream>>>(
        yg, W_out_b, 2048, 1024, 2048, 2048 / KSPL_O, out_part, nullptr, nullptr);
    reduce_out<<<LSEQ * D_MODEL / 4 / 256, 256, 0, stream>>>(out_part, x, (float*)d_out);
}

// Round 6
// 253.053 us; speedup vs baseline: 7.2719x; 1.0502x over previous
//
#include <hip/hip_runtime.h>
#include <hip/hip_bf16.h>

#define D_MODEL 1024
#define D_INNER 2048
#define DT_RANK 64
#define D_STATE 16
#define LSEQ    2048
#define CHUNK   32
#define NCHUNK  (LSEQ / CHUNK)       // 64
#define DN      (D_INNER * D_STATE)  // 32768
#define KSPL_O  4                    // split-K for out-proj
#define KSPL_X  16                   // split-K for x-proj

typedef __attribute__((ext_vector_type(8))) short  short8;
typedef __attribute__((ext_vector_type(4))) float  float4v;
typedef __hip_bfloat16 bf16;

static __device__ __forceinline__ float b2f(bf16 v) { return __bfloat162float(v); }
static __device__ __forceinline__ bf16  f2b(float v) { return __float2bfloat16(v); }

#define GLOAD_LDS16(g, l)                                                          \
    __builtin_amdgcn_global_load_lds((const __attribute__((address_space(1))) void*)(g), \
                                     (__attribute__((address_space(3))) void*)(l), 16, 0, 0)

// ---------------------- fused prep: RMSNorm (blocks 0..2047) + weight casts ----
#define N1 (2 * D_INNER * D_MODEL)   // W_in
#define N2 (D_MODEL * D_INNER)       // W_out
#define N3 (96 * D_INNER)            // W_xproj
#define N4 (D_INNER * DT_RANK)       // W_dt
#define NCAST4 ((N1 + N2 + N3 + N4) / 4)
__global__ __launch_bounds__(256)
void prep_kernel(const float* __restrict__ x, const float* __restrict__ nw,
                 bf16* __restrict__ xn,
                 const float* __restrict__ w_in, const float* __restrict__ w_out,
                 const float* __restrict__ w_xp, const float* __restrict__ w_dt,
                 bf16* __restrict__ o_in, bf16* __restrict__ o_out,
                 bf16* __restrict__ o_xp, bf16* __restrict__ o_dt) {
    int t = threadIdx.x;
    if (blockIdx.x < LSEQ) {   // RMSNorm row
        int l = blockIdx.x;
        float4v v = ((const float4v*)(x + (size_t)l * D_MODEL))[t];
        float ssq = v[0]*v[0] + v[1]*v[1] + v[2]*v[2] + v[3]*v[3];
        for (int o = 32; o > 0; o >>= 1) ssq += __shfl_down(ssq, o);
        __shared__ float part[4];
        int lane = t & 63, wid = t >> 6;
        if (lane == 0) part[wid] = ssq;
        __syncthreads();
        float tot = part[0] + part[1] + part[2] + part[3];
        float sc = rsqrtf(tot * (1.0f / D_MODEL) + 1e-5f);
        float4v nv = ((const float4v*)nw)[t];
        bf16* op = xn + (size_t)l * D_MODEL + t * 4;
        op[0] = f2b(v[0] * sc * nv[0]);
        op[1] = f2b(v[1] * sc * nv[1]);
        op[2] = f2b(v[2] * sc * nv[2]);
        op[3] = f2b(v[3] * sc * nv[3]);
        return;
    }
    int i4 = (blockIdx.x - LSEQ) * 256 + t;
    if (i4 >= NCAST4) return;
    const float* src; bf16* dst; int base;
    if (i4 < N1 / 4)                { src = w_in;  dst = o_in;  base = 0; }
    else if (i4 < (N1 + N2) / 4)    { src = w_out; dst = o_out; base = N1 / 4; }
    else if (i4 < (N1+N2+N3) / 4)   { src = w_xp;  dst = o_xp;  base = (N1+N2) / 4; }
    else                            { src = w_dt;  dst = o_dt;  base = (N1+N2+N3) / 4; }
    int j = i4 - base;
    float4v v = ((const float4v*)src)[j];
    bf16* o = dst + j * 4;
    o[0] = f2b(v[0]); o[1] = f2b(v[1]); o[2] = f2b(v[2]); o[3] = f2b(v[3]);
}

// ------------------- fast NT GEMM, BK=64, double-buffered, XOR-swizzled LDS ---
// C[M,N] = A[M,K]*B[N,K]^T. Tiles 128x128. K%64==0 (or kLen==64 single-shot).
// LDS physical chunk (16B) = logical chunk ^ (row&7): conflict-free stage+read.
// MODE 0: outB = bf16(acc)                       (xz)
// MODE 2: outB = bf16(softplus(acc+bias[n]))     (delta)
// MODE 4: outF[z-slice] = acc                    (split-K partials)
template <int MODE>
__global__ __launch_bounds__(256)
void gemm_fast(const bf16* __restrict__ Ab, const bf16* __restrict__ Bb,
               int M, int N, int K, int kLen,
               float* __restrict__ outF, bf16* __restrict__ outB,
               const float* __restrict__ bias) {
    __shared__ short As[2][128 * 64];   // 16 KB per buffer
    __shared__ short Bs[2][128 * 64];
    const short* Ap = (const short*)Ab;
    const short* Bp = (const short*)Bb;

    int t = threadIdx.x;
    int lane = t & 63, wid = t >> 6;
    int mBase = blockIdx.y * 128, nBase = blockIdx.x * 128;
    int kBase = blockIdx.z * kLen;
    int wm = (wid >> 1) * 64, wn = (wid & 1) * 64;
    int lr = lane & 15, quad = lane >> 4;

    // staging: wave wid owns rows [32*wid, 32*wid+32); 4 instrs of 8 rows each.
    // lane i -> row slab + (i>>3), physical chunk i&7, global chunk (i&7)^(i>>3).
    int srow = 32 * wid + (lane >> 3);
    int cg = (lane & 7) ^ (lane >> 3);
    const short* gA = Ap + (size_t)(mBase + srow) * K + cg * 8;
    const short* gB = Bp + (size_t)(nBase + srow) * K + cg * 8;

    float4v acc[4][4] = {};

    // prologue: stage first K-slab into buf 0
    #pragma unroll
    for (int g = 0; g < 4; ++g) {
        GLOAD_LDS16(gA + (size_t)g * 8 * K + kBase, &As[0][(32 * wid + g * 8) * 64]);
        GLOAD_LDS16(gB + (size_t)g * 8 * K + kBase, &Bs[0][(32 * wid + g * 8) * 64]);
    }

    int p = 0;
    for (int kt = kBase; kt < kBase + kLen; kt += 64, p ^= 1) {
        __syncthreads();   // drains buf[p] loads; all waves past buf[p^1] reads
        if (kt + 64 < kBase + kLen) {
            int kn = kt + 64, q = p ^ 1;
            #pragma unroll
            for (int g = 0; g < 4; ++g) {
                GLOAD_LDS16(gA + (size_t)g * 8 * K + kn, &As[q][(32 * wid + g * 8) * 64]);
                GLOAD_LDS16(gB + (size_t)g * 8 * K + kn, &Bs[q][(32 * wid + g * 8) * 64]);
            }
        }
        #pragma unroll
        for (int s = 0; s < 2; ++s) {
            short8 af[4], bfr[4];
            #pragma unroll
            for (int i = 0; i < 4; ++i) {
                int row = wm + i * 16 + lr;
                af[i] = *(const short8*)&As[p][row * 64 + (((s * 4 + quad) ^ (lr & 7)) * 8)];
            }
            #pragma unroll
            for (int j = 0; j < 4; ++j) {
                int row = wn + j * 16 + lr;
                bfr[j] = *(const short8*)&Bs[p][row * 64 + (((s * 4 + quad) ^ (lr & 7)) * 8)];
            }
            #pragma unroll
            for (int i = 0; i < 4; ++i)
                #pragma unroll
                for (int j = 0; j < 4; ++j)
                    acc[i][j] = __builtin_amdgcn_mfma_f32_16x16x32_bf16(af[i], bfr[j], acc[i][j], 0, 0, 0);
        }
    }

    #pragma unroll
    for (int i = 0; i < 4; ++i) {
        #pragma unroll
        for (int j = 0; j < 4; ++j) {
            #pragma unroll
            for (int r = 0; r < 4; ++r) {
                int gm = mBase + wm + i * 16 + quad * 4 + r;
                int gn = nBase + wn + j * 16 + lr;
                float v = acc[i][j][r];
                if (MODE == 0) {
                    outB[(size_t)gm * N + gn] = f2b(v);
                } else if (MODE == 2) {
                    v += bias[gn];
                    v = (v > 20.0f) ? v : log1pf(__expf(v));
                    outB[(size_t)gm * N + gn] = f2b(v);
                } else {  // MODE 4: split-K partials
                    outF[((size_t)blockIdx.z * M + gm) * N + gn] = v;
                }
            }
        }
    }
}

// --------------- x_proj reduce: dbc = sum_z part, + dt bf16 cast (fused) ------
__global__ __launch_bounds__(128)
void reduce_xproj(const float* __restrict__ part, float* __restrict__ dbc,
                  bf16* __restrict__ dtb) {
    int m = blockIdx.x, j = threadIdx.x;
    if (j >= 96) return;
    float v = 0.0f;
    #pragma unroll
    for (int z = 0; z < KSPL_X; ++z)
        v += part[((size_t)z * LSEQ + m) * 128 + j];
    dbc[(size_t)m * 96 + j] = v;
    if (j < DT_RANK) dtb[(size_t)m * DT_RANK + j] = f2b(v);
}

// --------------- out reduce: d_out = sum_z part + x (residual fused) ----------
__global__ __launch_bounds__(256)
void reduce_out(const float* __restrict__ part, const float* __restrict__ x,
                float* __restrict__ out) {
    int i = blockIdx.x * 256 + threadIdx.x;   // float4 over M*N/4
    const int MN4 = LSEQ * D_MODEL / 4;
    float4v a = ((const float4v*)part)[i];
    #pragma unroll
    for (int z = 1; z < KSPL_O; ++z) {
        float4v b = ((const float4v*)part)[(size_t)z * MN4 + i];
        a[0] += b[0]; a[1] += b[1]; a[2] += b[2]; a[3] += b[3];
    }
    float4v xv = ((const float4v*)x)[i];
    a[0] += xv[0]; a[1] += xv[1]; a[2] += xv[2]; a[3] += xv[3];
    ((float4v*)out)[i] = a;
}

// ---------------------- depthwise causal conv+SiLU, 4 timesteps per thread ----
__global__ void conv_kernel(const bf16* __restrict__ xz, const float* __restrict__ cw,
                            const float* __restrict__ cb, bf16* __restrict__ xsb) {
    int idx = blockIdx.x * 256 + threadIdx.x;   // over (LSEQ/4)*D_INNER
    int c = idx & (D_INNER - 1);
    int l0 = (idx >> 11) * 4;
    float w0 = cw[c * 4 + 0], w1 = cw[c * 4 + 1];
    float w2 = cw[c * 4 + 2], w3 = cw[c * 4 + 3];
    float b = cb[c];
    const bf16* col = xz + c;                   // row stride 2*D_INNER
    float v[7];
    #pragma unroll
    for (int j = 0; j < 7; ++j) {
        int l = l0 - 3 + j;
        v[j] = (l >= 0) ? b2f(col[(size_t)l * (2 * D_INNER)]) : 0.0f;
    }
    #pragma unroll
    for (int j = 0; j < 4; ++j) {
        float acc = b + v[j] * w0 + v[j + 1] * w1 + v[j + 2] * w2 + v[j + 3] * w3;
        float s = acc * (1.0f / (1.0f + __expf(-acc)));
        xsb[(size_t)(l0 + j) * D_INNER + c] = f2b(s);
    }
}

// ------------------------------- chunked selective scan, states in registers --
template <int PASS>
__global__ __launch_bounds__(256)
void scan2(const bf16* __restrict__ delta, const bf16* __restrict__ xsb,
           const float* __restrict__ dbc, const bf16* __restrict__ xz,
           const float* __restrict__ A_log, const float* __restrict__ Dw,
           const float* __restrict__ Hinit,
           float* __restrict__ P, float* __restrict__ S, bf16* __restrict__ yg) {
    __shared__ float bc[CHUNK][32];   // [l][B(16)|C(16)]
    int t = threadIdx.x;
    int d = blockIdx.x * 256 + t;
    int c = blockIdx.y;
    int l0 = c * CHUNK;

    {   // stage B,C for this chunk: 32 rows x 32 floats = 4 KB
        int row = t >> 3, col = (t & 7) * 4;
        *(float4v*)&bc[row][col] = *(const float4v*)&dbc[(size_t)(l0 + row) * 96 + 64 + col];
    }
    __syncthreads();

    float A[16], h[16], pr[16];
    #pragma unroll
    for (int n = 0; n < 16; ++n) A[n] = -__expf(A_log[(size_t)d * 16 + n]);
    if (PASS == 0) {
        #pragma unroll
        for (int n = 0; n < 16; ++n) { h[n] = 0.0f; pr[n] = 1.0f; }
    } else {
        #pragma unroll
        for (int n = 0; n < 16; n += 4)
            *(float4v*)&h[n] = *(const float4v*)&Hinit[(size_t)c * DN + (size_t)d * 16 + n];
    }
    float Dd = (PASS == 1) ? Dw[d] : 0.0f;

    for (int i = 0; i < CHUNK; ++i) {
        int l = l0 + i;
        float dv = b2f(delta[(size_t)l * D_INNER + d]);
        float xv = b2f(xsb[(size_t)l * D_INNER + d]);
        float u = dv * xv;
        float Bv[16];
        #pragma unroll
        for (int n = 0; n < 16; n += 4) *(float4v*)&Bv[n] = *(const float4v*)&bc[i][n];
        #pragma unroll
        for (int n = 0; n < 16; ++n) {
            float a = __expf(dv * A[n]);
            h[n] = fmaf(a, h[n], Bv[n] * u);
            if (PASS == 0) pr[n] *= a;
        }
        if (PASS == 1) {
            float Cv[16];
            #pragma unroll
            for (int n = 0; n < 16; n += 4) *(float4v*)&Cv[n] = *(const float4v*)&bc[i][16 + n];
            float y = xv * Dd;
            #pragma unroll
            for (int n = 0; n < 16; ++n) y = fmaf(h[n], Cv[n], y);
            float r = b2f(xz[(size_t)l * (2 * D_INNER) + D_INNER + d]);
            float g = r * (1.0f / (1.0f + __expf(-r)));
            yg[(size_t)l * D_INNER + d] = f2b(y * g);
        }
    }
    if (PASS == 0) {
        #pragma unroll
        for (int n = 0; n < 16; n += 4) {
            *(float4v*)&P[(size_t)c * DN + (size_t)d * 16 + n] = *(float4v*)&pr[n];
            *(float4v*)&S[(size_t)c * DN + (size_t)d * 16 + n] = *(float4v*)&h[n];
        }
    }
}

// Sequential compose over chunks: h_init[c+1] = P[c]*h_init[c] + S[c].
__global__ __launch_bounds__(256)
void scan_mid(const float* __restrict__ P, const float* __restrict__ S,
              float* __restrict__ Hinit) {
    int idx = blockIdx.x * 256 + threadIdx.x;   // over DN
    float h = 0.0f;
    for (int c0 = 0; c0 < NCHUNK; c0 += 8) {
        float p[8], s[8];
        #pragma unroll
        for (int j = 0; j < 8; ++j) {
            p[j] = P[(size_t)(c0 + j) * DN + idx];
            s[j] = S[(size_t)(c0 + j) * DN + idx];
        }
        #pragma unroll
        for (int j = 0; j < 8; ++j) {
            Hinit[(size_t)(c0 + j) * DN + idx] = h;
            h = fmaf(p[j], h, s[j]);
        }
    }
}

// -------------------------------------------------------------- launcher ----
extern "C" void kernel_launch(void* const* d_in, const int* in_sizes, int n_in,
                              void* d_out, int out_size, void* d_ws, size_t ws_size,
                              hipStream_t stream) {
    const float* x       = (const float*)d_in[0];
    const float* W_in    = (const float*)d_in[1];
    const float* conv_w  = (const float*)d_in[2];
    const float* conv_b  = (const float*)d_in[3];
    const float* W_xproj = (const float*)d_in[4];
    const float* W_dt    = (const float*)d_in[5];
    const float* b_dt    = (const float*)d_in[6];
    const float* A_log   = (const float*)d_in[7];
    const float* Dw      = (const float*)d_in[8];
    const float* W_out   = (const float*)d_in[9];
    const float* norm_w  = (const float*)d_in[10];

    char* w = (char*)d_ws;
    bf16* W_in_b    = (bf16*)w; w += (size_t)2 * D_INNER * D_MODEL * 2;   // 8 MB
    bf16* W_out_b   = (bf16*)w; w += (size_t)D_MODEL * D_INNER * 2;       // 4 MB
    bf16* W_xproj_b = (bf16*)w; w += (size_t)128 * D_INNER * 2;           // 512 KB (rows 96..127 pad)
    bf16* W_dt_b    = (bf16*)w; w += (size_t)D_INNER * DT_RANK * 2;       // 256 KB
    char* reuse0 = w;   // aliased by out_part after scan pass 1
    bf16* xn        = (bf16*)w; w += (size_t)LSEQ * D_MODEL * 2;          // 4 MB
    bf16* xz        = (bf16*)w; w += (size_t)LSEQ * 2 * D_INNER * 2;      // 16 MB
    bf16* xsb       = (bf16*)w; w += (size_t)LSEQ * D_INNER * 2;          // 8 MB
    bf16* delta     = (bf16*)w; w += (size_t)LSEQ * D_INNER * 2;          // 8 MB  (36 MB pool)
    float* dbc      = (float*)w; w += (size_t)LSEQ * 96 * 4;              // 768 KB
    bf16* dtb       = (bf16*)w; w += (size_t)LSEQ * DT_RANK * 2;          // 256 KB
    bf16* yg        = (bf16*)w; w += (size_t)LSEQ * D_INNER * 2;          // 8 MB
    float* Pbuf     = (float*)w; w += (size_t)NCHUNK * DN * 4;            // 8 MB
    float* Sbuf     = (float*)w; w += (size_t)NCHUNK * DN * 4;            // 8 MB
    float* Hinit    = (float*)w; w += (size_t)NCHUNK * DN * 4;            // 8 MB
    float* xp_part  = (float*)w; w += (size_t)KSPL_X * LSEQ * 128 * 4;    // 16 MB
    float* out_part = (float*)reuse0;   // 32 MB

    prep_kernel<<<LSEQ + (NCAST4 + 255) / 256, 256, 0, stream>>>(
        x, norm_w, xn, W_in, W_out, W_xproj, W_dt, W_in_b, W_out_b, W_xproj_b, W_dt_b);

    // in_proj: (2048 x 4096) = xn (2048x1024) * W_in^T
    gemm_fast<0><<<dim3(4096 / 128, 2048 / 128, 1), 256, 0, stream>>>(
        xn, W_in_b, 2048, 4096, 1024, 1024, nullptr, xz, nullptr);

    conv_kernel<<<(LSEQ / 4 * D_INNER) / 256, 256, 0, stream>>>(xz, conv_w, conv_b, xsb);

    // x_proj: (2048 x 96) = xsb (2048x2048) * W_xproj^T, split-K=16, N padded to 128
    gemm_fast<4><<<dim3(1, 2048 / 128, KSPL_X), 256, 0, stream>>>(
        xsb, W_xproj_b, 2048, 128, 2048, 2048 / KSPL_X, xp_part, nullptr, nullptr);
    reduce_xproj<<<LSEQ, 128, 0, stream>>>(xp_part, dbc, dtb);

    // delta: (2048 x 2048) = dtb (2048x64) * W_dt^T, softplus+bias epilogue
    gemm_fast<2><<<dim3(2048 / 128, 2048 / 128, 1), 256, 0, stream>>>(
        dtb, W_dt_b, 2048, 2048, 64, 64, nullptr, delta, b_dt);

    dim3 sgrid(D_INNER / 256, NCHUNK);
    scan2<0><<<sgrid, 256, 0, stream>>>(delta, xsb, dbc, xz, A_log, Dw,
                                        nullptr, Pbuf, Sbuf, nullptr);
    scan_mid<<<DN / 256, 256, 0, stream>>>(Pbuf, Sbuf, Hinit);
    scan2<1><<<sgrid, 256, 0, stream>>>(delta, xsb, dbc, xz, A_log, Dw,
                                        Hinit, nullptr, nullptr, yg);

    // out_proj: (2048 x 1024) = yg (2048x2048) * W_out^T, split-K=4
    gemm_fast<4><<<dim3(1024 / 128, 2048 / 128, KSPL_O), 256, 0, stream>>>(
        yg, W_out_b, 2048, 1024, 2048, 2048 / KSPL_O, out_part, nullptr, nullptr);
    reduce_out<<<LSEQ * D_MODEL / 4 / 256, 256, 0, stream>>>(out_part, x, (float*)d_out);
}

// Round 7
// 242.038 us; speedup vs baseline: 7.6028x; 1.0455x over previous
//
#include <hip/hip_runtime.h>
#include <hip/hip_bf16.h>

#define D_MODEL 1024
#define D_INNER 2048
#define DT_RANK 64
#define D_STATE 16
#define LSEQ    2048
#define CHUNK   32
#define NCHUNK  (LSEQ / CHUNK)       // 64
#define DN      (D_INNER * D_STATE)  // 32768
#define KSPL_O  4                    // split-K for out-proj
#define KSPL_X  16                   // split-K for x-proj

typedef __attribute__((ext_vector_type(8))) short  short8;
typedef __attribute__((ext_vector_type(4))) float  float4v;
typedef __hip_bfloat16 bf16;

static __device__ __forceinline__ float b2f(bf16 v) { return __bfloat162float(v); }
static __device__ __forceinline__ bf16  f2b(float v) { return __float2bfloat16(v); }

#define GLOAD_LDS16(g, l)                                                          \
    __builtin_amdgcn_global_load_lds((const __attribute__((address_space(1))) void*)(g), \
                                     (__attribute__((address_space(3))) void*)(l), 16, 0, 0)

// ---------------------- fused prep: RMSNorm (blocks 0..2047) + weight casts ----
#define N1 (2 * D_INNER * D_MODEL)   // W_in
#define N2 (D_MODEL * D_INNER)       // W_out
#define N3 (96 * D_INNER)            // W_xproj
#define N4 (D_INNER * DT_RANK)       // W_dt
#define NCAST4 ((N1 + N2 + N3 + N4) / 4)
__global__ __launch_bounds__(256)
void prep_kernel(const float* __restrict__ x, const float* __restrict__ nw,
                 bf16* __restrict__ xn,
                 const float* __restrict__ w_in, const float* __restrict__ w_out,
                 const float* __restrict__ w_xp, const float* __restrict__ w_dt,
                 bf16* __restrict__ o_in, bf16* __restrict__ o_out,
                 bf16* __restrict__ o_xp, bf16* __restrict__ o_dt) {
    int t = threadIdx.x;
    if (blockIdx.x < LSEQ) {   // RMSNorm row
        int l = blockIdx.x;
        float4v v = ((const float4v*)(x + (size_t)l * D_MODEL))[t];
        float ssq = v[0]*v[0] + v[1]*v[1] + v[2]*v[2] + v[3]*v[3];
        for (int o = 32; o > 0; o >>= 1) ssq += __shfl_down(ssq, o);
        __shared__ float part[4];
        int lane = t & 63, wid = t >> 6;
        if (lane == 0) part[wid] = ssq;
        __syncthreads();
        float tot = part[0] + part[1] + part[2] + part[3];
        float sc = rsqrtf(tot * (1.0f / D_MODEL) + 1e-5f);
        float4v nv = ((const float4v*)nw)[t];
        bf16* op = xn + (size_t)l * D_MODEL + t * 4;
        op[0] = f2b(v[0] * sc * nv[0]);
        op[1] = f2b(v[1] * sc * nv[1]);
        op[2] = f2b(v[2] * sc * nv[2]);
        op[3] = f2b(v[3] * sc * nv[3]);
        return;
    }
    int i4 = (blockIdx.x - LSEQ) * 256 + t;
    if (i4 >= NCAST4) return;
    const float* src; bf16* dst; int base;
    if (i4 < N1 / 4)                { src = w_in;  dst = o_in;  base = 0; }
    else if (i4 < (N1 + N2) / 4)    { src = w_out; dst = o_out; base = N1 / 4; }
    else if (i4 < (N1+N2+N3) / 4)   { src = w_xp;  dst = o_xp;  base = (N1+N2) / 4; }
    else                            { src = w_dt;  dst = o_dt;  base = (N1+N2+N3) / 4; }
    int j = i4 - base;
    float4v v = ((const float4v*)src)[j];
    bf16* o = dst + j * 4;
    o[0] = f2b(v[0]); o[1] = f2b(v[1]); o[2] = f2b(v[2]); o[3] = f2b(v[3]);
}

// ---- fast NT GEMM: 512 threads / 8 waves, wave tile 32x64, BK=64, dbuf LDS ---
// C[M,N] = A[M,K]*B[N,K]^T. Tiles 128x128. kLen%64==0.
// LDS physical 16B-chunk = logical chunk ^ (row&7) -> conflict-free stage+read.
// MODE 0: outB = bf16(acc)                       (xz)
// MODE 2: outB = bf16(softplus(acc+bias[n]))     (delta)
// MODE 4: outF[z-slice] = acc                    (split-K partials)
template <int MODE>
__global__ __launch_bounds__(512)
void gemm_fast(const bf16* __restrict__ Ab, const bf16* __restrict__ Bb,
               int M, int N, int K, int kLen,
               float* __restrict__ outF, bf16* __restrict__ outB,
               const float* __restrict__ bias) {
    __shared__ short As[2][128 * 64];   // 16 KB per buffer
    __shared__ short Bs[2][128 * 64];
    const short* Ap = (const short*)Ab;
    const short* Bp = (const short*)Bb;

    int t = threadIdx.x;
    int lane = t & 63, wid = t >> 6;            // 8 waves
    int mBase = blockIdx.y * 128, nBase = blockIdx.x * 128;
    int kBase = blockIdx.z * kLen;
    int wm = 32 * (wid >> 1), wn = 64 * (wid & 1);   // wave tile 32x64
    int lr = lane & 15, quad = lane >> 4;

    // staging: wave wid owns rows [16*wid, 16*wid+16); 2 instrs of 8 rows each.
    int srow = 16 * wid + (lane >> 3);
    int cg = (lane & 7) ^ (lane >> 3);          // global chunk for phys chunk lane&7
    const short* gA = Ap + (size_t)(mBase + srow) * K + cg * 8;
    const short* gB = Bp + (size_t)(nBase + srow) * K + cg * 8;

    float4v acc[2][4] = {};

    // prologue: stage first K-slab into buf 0
    #pragma unroll
    for (int g = 0; g < 2; ++g) {
        GLOAD_LDS16(gA + (size_t)g * 8 * K + kBase, &As[0][(16 * wid + g * 8) * 64]);
        GLOAD_LDS16(gB + (size_t)g * 8 * K + kBase, &Bs[0][(16 * wid + g * 8) * 64]);
    }

    int p = 0;
    for (int kt = kBase; kt < kBase + kLen; kt += 64, p ^= 1) {
        __syncthreads();   // drains buf[p] loads; all waves past buf[p^1] reads
        if (kt + 64 < kBase + kLen) {
            int kn = kt + 64, q = p ^ 1;
            #pragma unroll
            for (int g = 0; g < 2; ++g) {
                GLOAD_LDS16(gA + (size_t)g * 8 * K + kn, &As[q][(16 * wid + g * 8) * 64]);
                GLOAD_LDS16(gB + (size_t)g * 8 * K + kn, &Bs[q][(16 * wid + g * 8) * 64]);
            }
        }
        #pragma unroll
        for (int s = 0; s < 2; ++s) {
            short8 af[2], bfr[4];
            #pragma unroll
            for (int i = 0; i < 2; ++i) {
                int row = wm + i * 16 + lr;
                af[i] = *(const short8*)&As[p][row * 64 + (((s * 4 + quad) ^ (lr & 7)) * 8)];
            }
            #pragma unroll
            for (int j = 0; j < 4; ++j) {
                int row = wn + j * 16 + lr;
                bfr[j] = *(const short8*)&Bs[p][row * 64 + (((s * 4 + quad) ^ (lr & 7)) * 8)];
            }
            #pragma unroll
            for (int i = 0; i < 2; ++i)
                #pragma unroll
                for (int j = 0; j < 4; ++j)
                    acc[i][j] = __builtin_amdgcn_mfma_f32_16x16x32_bf16(af[i], bfr[j], acc[i][j], 0, 0, 0);
        }
    }

    #pragma unroll
    for (int i = 0; i < 2; ++i) {
        #pragma unroll
        for (int j = 0; j < 4; ++j) {
            #pragma unroll
            for (int r = 0; r < 4; ++r) {
                int gm = mBase + wm + i * 16 + quad * 4 + r;
                int gn = nBase + wn + j * 16 + lr;
                float v = acc[i][j][r];
                if (MODE == 0) {
                    outB[(size_t)gm * N + gn] = f2b(v);
                } else if (MODE == 2) {
                    v += bias[gn];
                    v = (v > 20.0f) ? v : log1pf(__expf(v));
                    outB[(size_t)gm * N + gn] = f2b(v);
                } else {  // MODE 4: split-K partials
                    outF[((size_t)blockIdx.z * M + gm) * N + gn] = v;
                }
            }
        }
    }
}

// --------------- x_proj reduce: dbc = sum_z part, + dt bf16 cast (fused) ------
__global__ __launch_bounds__(128)
void reduce_xproj(const float* __restrict__ part, float* __restrict__ dbc,
                  bf16* __restrict__ dtb) {
    int m = blockIdx.x, j = threadIdx.x;
    if (j >= 96) return;
    float v = 0.0f;
    #pragma unroll
    for (int z = 0; z < KSPL_X; ++z)
        v += part[((size_t)z * LSEQ + m) * 128 + j];
    dbc[(size_t)m * 96 + j] = v;
    if (j < DT_RANK) dtb[(size_t)m * DT_RANK + j] = f2b(v);
}

// --------------- out reduce: d_out = sum_z part + x (residual fused) ----------
__global__ __launch_bounds__(256)
void reduce_out(const float* __restrict__ part, const float* __restrict__ x,
                float* __restrict__ out) {
    int i = blockIdx.x * 256 + threadIdx.x;   // float4 over M*N/4
    const int MN4 = LSEQ * D_MODEL / 4;
    float4v a = ((const float4v*)part)[i];
    #pragma unroll
    for (int z = 1; z < KSPL_O; ++z) {
        float4v b = ((const float4v*)part)[(size_t)z * MN4 + i];
        a[0] += b[0]; a[1] += b[1]; a[2] += b[2]; a[3] += b[3];
    }
    float4v xv = ((const float4v*)x)[i];
    a[0] += xv[0]; a[1] += xv[1]; a[2] += xv[2]; a[3] += xv[3];
    ((float4v*)out)[i] = a;
}

// ---------------------- depthwise causal conv+SiLU, 4 timesteps per thread ----
__global__ void conv_kernel(const bf16* __restrict__ xz, const float* __restrict__ cw,
                            const float* __restrict__ cb, bf16* __restrict__ xsb) {
    int idx = blockIdx.x * 256 + threadIdx.x;   // over (LSEQ/4)*D_INNER
    int c = idx & (D_INNER - 1);
    int l0 = (idx >> 11) * 4;
    float w0 = cw[c * 4 + 0], w1 = cw[c * 4 + 1];
    float w2 = cw[c * 4 + 2], w3 = cw[c * 4 + 3];
    float b = cb[c];
    const bf16* col = xz + c;                   // row stride 2*D_INNER
    float v[7];
    #pragma unroll
    for (int j = 0; j < 7; ++j) {
        int l = l0 - 3 + j;
        v[j] = (l >= 0) ? b2f(col[(size_t)l * (2 * D_INNER)]) : 0.0f;
    }
    #pragma unroll
    for (int j = 0; j < 4; ++j) {
        float acc = b + v[j] * w0 + v[j + 1] * w1 + v[j + 2] * w2 + v[j + 3] * w3;
        float s = acc * (1.0f / (1.0f + __expf(-acc)));
        xsb[(size_t)(l0 + j) * D_INNER + c] = f2b(s);
    }
}

// ------------------------------- chunked selective scan, states in registers --
template <int PASS>
__global__ __launch_bounds__(256)
void scan2(const bf16* __restrict__ delta, const bf16* __restrict__ xsb,
           const float* __restrict__ dbc, const bf16* __restrict__ xz,
           const float* __restrict__ A_log, const float* __restrict__ Dw,
           const float* __restrict__ Hinit,
           float* __restrict__ P, float* __restrict__ S, bf16* __restrict__ yg) {
    __shared__ float bc[CHUNK][32];   // [l][B(16)|C(16)]
    int t = threadIdx.x;
    int d = blockIdx.x * 256 + t;
    int c = blockIdx.y;
    int l0 = c * CHUNK;

    {   // stage B,C for this chunk: 32 rows x 32 floats = 4 KB
        int row = t >> 3, col = (t & 7) * 4;
        *(float4v*)&bc[row][col] = *(const float4v*)&dbc[(size_t)(l0 + row) * 96 + 64 + col];
    }
    __syncthreads();

    float A[16], h[16], pr[16];
    #pragma unroll
    for (int n = 0; n < 16; ++n) A[n] = -__expf(A_log[(size_t)d * 16 + n]);
    if (PASS == 0) {
        #pragma unroll
        for (int n = 0; n < 16; ++n) { h[n] = 0.0f; pr[n] = 1.0f; }
    } else {
        #pragma unroll
        for (int n = 0; n < 16; n += 4)
            *(float4v*)&h[n] = *(const float4v*)&Hinit[(size_t)c * DN + (size_t)d * 16 + n];
    }
    float Dd = (PASS == 1) ? Dw[d] : 0.0f;

    for (int i = 0; i < CHUNK; ++i) {
        int l = l0 + i;
        float dv = b2f(delta[(size_t)l * D_INNER + d]);
        float xv = b2f(xsb[(size_t)l * D_INNER + d]);
        float u = dv * xv;
        float Bv[16];
        #pragma unroll
        for (int n = 0; n < 16; n += 4) *(float4v*)&Bv[n] = *(const float4v*)&bc[i][n];
        #pragma unroll
        for (int n = 0; n < 16; ++n) {
            float a = __expf(dv * A[n]);
            h[n] = fmaf(a, h[n], Bv[n] * u);
            if (PASS == 0) pr[n] *= a;
        }
        if (PASS == 1) {
            float Cv[16];
            #pragma unroll
            for (int n = 0; n < 16; n += 4) *(float4v*)&Cv[n] = *(const float4v*)&bc[i][16 + n];
            float y = xv * Dd;
            #pragma unroll
            for (int n = 0; n < 16; ++n) y = fmaf(h[n], Cv[n], y);
            float r = b2f(xz[(size_t)l * (2 * D_INNER) + D_INNER + d]);
            float g = r * (1.0f / (1.0f + __expf(-r)));
            yg[(size_t)l * D_INNER + d] = f2b(y * g);
        }
    }
    if (PASS == 0) {
        #pragma unroll
        for (int n = 0; n < 16; n += 4) {
            *(float4v*)&P[(size_t)c * DN + (size_t)d * 16 + n] = *(float4v*)&pr[n];
            *(float4v*)&S[(size_t)c * DN + (size_t)d * 16 + n] = *(float4v*)&h[n];
        }
    }
}

// Sequential compose over chunks: h_init[c+1] = P[c]*h_init[c] + S[c].
__global__ __launch_bounds__(256)
void scan_mid(const float* __restrict__ P, const float* __restrict__ S,
              float* __restrict__ Hinit) {
    int idx = blockIdx.x * 256 + threadIdx.x;   // over DN
    float h = 0.0f;
    for (int c0 = 0; c0 < NCHUNK; c0 += 8) {
        float p[8], s[8];
        #pragma unroll
        for (int j = 0; j < 8; ++j) {
            p[j] = P[(size_t)(c0 + j) * DN + idx];
            s[j] = S[(size_t)(c0 + j) * DN + idx];
        }
        #pragma unroll
        for (int j = 0; j < 8; ++j) {
            Hinit[(size_t)(c0 + j) * DN + idx] = h;
            h = fmaf(p[j], h, s[j]);
        }
    }
}

// -------------------------------------------------------------- launcher ----
extern "C" void kernel_launch(void* const* d_in, const int* in_sizes, int n_in,
                              void* d_out, int out_size, void* d_ws, size_t ws_size,
                              hipStream_t stream) {
    const float* x       = (const float*)d_in[0];
    const float* W_in    = (const float*)d_in[1];
    const float* conv_w  = (const float*)d_in[2];
    const float* conv_b  = (const float*)d_in[3];
    const float* W_xproj = (const float*)d_in[4];
    const float* W_dt    = (const float*)d_in[5];
    const float* b_dt    = (const float*)d_in[6];
    const float* A_log   = (const float*)d_in[7];
    const float* Dw      = (const float*)d_in[8];
    const float* W_out   = (const float*)d_in[9];
    const float* norm_w  = (const float*)d_in[10];

    char* w = (char*)d_ws;
    bf16* W_in_b    = (bf16*)w; w += (size_t)2 * D_INNER * D_MODEL * 2;   // 8 MB
    bf16* W_out_b   = (bf16*)w; w += (size_t)D_MODEL * D_INNER * 2;       // 4 MB
    bf16* W_xproj_b = (bf16*)w; w += (size_t)128 * D_INNER * 2;           // 512 KB (rows 96..127 pad)
    bf16* W_dt_b    = (bf16*)w; w += (size_t)D_INNER * DT_RANK * 2;       // 256 KB
    char* reuse0 = w;   // aliased by out_part after scan pass 1
    bf16* xn        = (bf16*)w; w += (size_t)LSEQ * D_MODEL * 2;          // 4 MB
    bf16* xz        = (bf16*)w; w += (size_t)LSEQ * 2 * D_INNER * 2;      // 16 MB
    bf16* xsb       = (bf16*)w; w += (size_t)LSEQ * D_INNER * 2;          // 8 MB
    bf16* delta     = (bf16*)w; w += (size_t)LSEQ * D_INNER * 2;          // 8 MB  (36 MB pool)
    float* dbc      = (float*)w; w += (size_t)LSEQ * 96 * 4;              // 768 KB
    bf16* dtb       = (bf16*)w; w += (size_t)LSEQ * DT_RANK * 2;          // 256 KB
    bf16* yg        = (bf16*)w; w += (size_t)LSEQ * D_INNER * 2;          // 8 MB
    float* Pbuf     = (float*)w; w += (size_t)NCHUNK * DN * 4;            // 8 MB
    float* Sbuf     = (float*)w; w += (size_t)NCHUNK * DN * 4;            // 8 MB
    float* Hinit    = (float*)w; w += (size_t)NCHUNK * DN * 4;            // 8 MB
    float* xp_part  = (float*)w; w += (size_t)KSPL_X * LSEQ * 128 * 4;    // 16 MB
    float* out_part = (float*)reuse0;   // 32 MB

    prep_kernel<<<LSEQ + (NCAST4 + 255) / 256, 256, 0, stream>>>(
        x, norm_w, xn, W_in, W_out, W_xproj, W_dt, W_in_b, W_out_b, W_xproj_b, W_dt_b);

    // in_proj: (2048 x 4096) = xn (2048x1024) * W_in^T
    gemm_fast<0><<<dim3(4096 / 128, 2048 / 128, 1), 512, 0, stream>>>(
        xn, W_in_b, 2048, 4096, 1024, 1024, nullptr, xz, nullptr);

    conv_kernel<<<(LSEQ / 4 * D_INNER) / 256, 256, 0, stream>>>(xz, conv_w, conv_b, xsb);

    // x_proj: (2048 x 96) = xsb (2048x2048) * W_xproj^T, split-K=16, N padded to 128
    gemm_fast<4><<<dim3(1, 2048 / 128, KSPL_X), 512, 0, stream>>>(
        xsb, W_xproj_b, 2048, 128, 2048, 2048 / KSPL_X, xp_part, nullptr, nullptr);
    reduce_xproj<<<LSEQ, 128, 0, stream>>>(xp_part, dbc, dtb);

    // delta: (2048 x 2048) = dtb (2048x64) * W_dt^T, softplus+bias epilogue
    gemm_fast<2><<<dim3(2048 / 128, 2048 / 128, 1), 512, 0, stream>>>(
        dtb, W_dt_b, 2048, 2048, 64, 64, nullptr, delta, b_dt);

    dim3 sgrid(D_INNER / 256, NCHUNK);
    scan2<0><<<sgrid, 256, 0, stream>>>(delta, xsb, dbc, xz, A_log, Dw,
                                        nullptr, Pbuf, Sbuf, nullptr);
    scan_mid<<<DN / 256, 256, 0, stream>>>(Pbuf, Sbuf, Hinit);
    scan2<1><<<sgrid, 256, 0, stream>>>(delta, xsb, dbc, xz, A_log, Dw,
                                        Hinit, nullptr, nullptr, yg);

    // out_proj: (2048 x 1024) = yg (2048x2048) * W_out^T, split-K=4
    gemm_fast<4><<<dim3(1024 / 128, 2048 / 128, KSPL_O), 512, 0, stream>>>(
        yg, W_out_b, 2048, 1024, 2048, 2048 / KSPL_O, out_part, nullptr, nullptr);
    reduce_out<<<LSEQ * D_MODEL / 4 / 256, 256, 0, stream>>>(out_part, x, (float*)d_out);
}